// Round 9
// baseline (3029.092 us; speedup 1.0000x reference)
//
#include <hip/hip_runtime.h>

// GIN round 9: edge-parallel fused conv stage-1. Bucketed edge list (ebuf) is
// consumed directly: per-block LDS fp32 accumulator tile (stride-65 bank
// spread) + ds_add_f32 atomics, then MFMA. bucket_csr / row / srcs deleted.
// Encoder & GEMM2 MFMA, bf16 h/m storage, folded BN, run-length pooling.

#define BN_EPS 1e-5f
#define CURS_STRIDE 16

typedef __attribute__((ext_vector_type(8))) short short8;
typedef __attribute__((ext_vector_type(4))) float f32x4;

// ---- bf16 helpers (rne) ----
__device__ __forceinline__ unsigned int pack_bf16x2(float a, float b) {
    unsigned int ua = __float_as_uint(a);
    unsigned int ub = __float_as_uint(b);
    ua = (ua + 0x7FFFu + ((ua >> 16) & 1u)) >> 16;
    ub = (ub + 0x7FFFu + ((ub >> 16) & 1u)) >> 16;
    return ua | (ub << 16);
}
__device__ __forceinline__ unsigned short bf16_1(float f) {
    unsigned int u = __float_as_uint(f);
    u = (u + 0x7FFFu + ((u >> 16) & 1u)) >> 16;
    return (unsigned short)u;
}
__device__ __forceinline__ float2 unpack_bf16x2(unsigned int u) {
    float2 r;
    r.x = __uint_as_float(u << 16);
    r.y = __uint_as_float(u & 0xFFFF0000u);
    return r;
}

// accumulate 8 bf16 (with optional BN+ReLU) into LDS via ds_add_f32
template<bool BN>
__device__ __forceinline__ void lds_add8(float* a, uint4 p,
                                         const float* sc, const float* sh) {
    unsigned int pp[4] = {p.x, p.y, p.z, p.w};
    #pragma unroll
    for (int t = 0; t < 4; t++) {
        float2 f = unpack_bf16x2(pp[t]);
        if (BN) {
            f.x = fmaxf(fmaf(f.x, sc[2 * t],     sh[2 * t]),     0.f);
            f.y = fmaxf(fmaf(f.y, sc[2 * t + 1], sh[2 * t + 1]), 0.f);
        }
        atomicAdd(&a[2 * t],     f.x);
        atomicAdd(&a[2 * t + 1], f.y);
    }
}

// ---------------------------------------------------------------------------
// Fused GIN stage 1 (edge-parallel): block b owns dst rows [b*128, b*128+128)
// and edge range [bbase[b], bbase[b+1]) of ebuf = (src<<7)|dstloc.
// acc[dl][:] = t(hb[nb+dl]) + sum_edges t(hb[src]);  out = bf16(acc @ W + b).
template<bool BN>
__global__ __launch_bounds__(256)
void gin_gemm1(const int* __restrict__ bbase, const int* __restrict__ ebuf,
               const unsigned int* __restrict__ hb,
               const float* __restrict__ bsum, const float* __restrict__ bsumsq,
               const float* __restrict__ gamma, const float* __restrict__ beta,
               float invN,
               const float* __restrict__ W, const float* __restrict__ bias,
               unsigned short* __restrict__ out,
               float* __restrict__ stat_sum, float* __restrict__ stat_sumsq,
               int N)
{
    constexpr int ACS = 65;          // word stride: bank = (dl + col) % 32
    constexpr int WS  = 72, KH = 2;
    __shared__ float accs[128 * ACS];        // 33.3 KB fp32 accumulator
    __shared__ short wt_lds[64 * WS];
    __shared__ float ssf[128];
    __shared__ float red[512];

    const int tid = threadIdx.x;
    const int b   = blockIdx.x;
    const int nb  = b * 128;
    const int l   = tid & 63;
    const int w   = tid >> 6;
    const int ln  = l & 15;
    const int q   = l >> 4;
    const int cc  = tid & 7;         // col group (8 cols)
    const int rl  = tid >> 3;        // 0..31

    if (BN) {
        if (tid < 64) {
            float mu  = bsum[tid] * invN;
            float var = bsumsq[tid] * invN - mu * mu;
            float s   = gamma[tid] * rsqrtf(var + BN_EPS);
            ssf[tid]      = s;
            ssf[64 + tid] = beta[tid] - s * mu;
        }
        __syncthreads();
    }

    // stage W^T bf16
    for (int idx = tid; idx < 64 * 64; idx += 256) {
        int k = idx >> 6, n = idx & 63;
        wt_lds[n * WS + k] = (short)bf16_1(W[idx]);
    }

    float sc[8], sh[8];
    if (BN) {
        #pragma unroll
        for (int j = 0; j < 8; j++) {
            sc[j] = ssf[cc * 8 + j];
            sh[j] = ssf[64 + cc * 8 + j];
        }
    }

    // init acc with self-term (plain stores)
    const uint4* hb4 = (const uint4*)hb;
    #pragma unroll
    for (int it = 0; it < 4; it++) {
        int r = it * 32 + rl;
        int n = nb + r;
        float v[8] = {0.f, 0.f, 0.f, 0.f, 0.f, 0.f, 0.f, 0.f};
        if (n < N) {
            uint4 p = hb4[(size_t)n * 8 + cc];
            unsigned int pp[4] = {p.x, p.y, p.z, p.w};
            #pragma unroll
            for (int t = 0; t < 4; t++) {
                float2 f = unpack_bf16x2(pp[t]);
                if (BN) {
                    f.x = fmaxf(fmaf(f.x, sc[2 * t],     sh[2 * t]),     0.f);
                    f.y = fmaxf(fmaf(f.y, sc[2 * t + 1], sh[2 * t + 1]), 0.f);
                }
                v[2 * t] = f.x; v[2 * t + 1] = f.y;
            }
        }
        #pragma unroll
        for (int j = 0; j < 8; j++)
            accs[r * ACS + cc * 8 + j] = v[j];
    }
    __syncthreads();

    // edge phase: 8 lanes per edge, 32 edges per 256-thr step, 2-deep unroll
    {
        const int beg = bbase[b], end = bbase[b + 1];
        int e = beg + rl;
        for (; e + 32 < end; e += 64) {
            int pk0 = ebuf[e], pk1 = ebuf[e + 32];
            uint4 p0 = hb4[(size_t)(pk0 >> 7) * 8 + cc];
            uint4 p1 = hb4[(size_t)(pk1 >> 7) * 8 + cc];
            lds_add8<BN>(&accs[(pk0 & 127) * ACS + cc * 8], p0, sc, sh);
            lds_add8<BN>(&accs[(pk1 & 127) * ACS + cc * 8], p1, sc, sh);
        }
        if (e < end) {
            int pk0 = ebuf[e];
            uint4 p0 = hb4[(size_t)(pk0 >> 7) * 8 + cc];
            lds_add8<BN>(&accs[(pk0 & 127) * ACS + cc * 8], p0, sc, sh);
        }
    }
    __syncthreads();

    // MFMA: fragments from fp32 LDS with bf16 convert
    short8 afrag[2][KH], bfrag[4][KH];
    const int rw = w * 32;
    #pragma unroll
    for (int mt = 0; mt < 2; mt++)
        #pragma unroll
        for (int kh = 0; kh < KH; kh++) {
            const float* ap = &accs[(rw + mt * 16 + ln) * ACS + kh * 32 + q * 8];
            #pragma unroll
            for (int j = 0; j < 8; j++)
                afrag[mt][kh][j] = (short)bf16_1(ap[j]);
        }
    #pragma unroll
    for (int nt = 0; nt < 4; nt++)
        #pragma unroll
        for (int kh = 0; kh < KH; kh++)
            bfrag[nt][kh] = *(const short8*)&wt_lds[(nt * 16 + ln) * WS + kh * 32 + q * 8];

    f32x4 acc[2][4];
    #pragma unroll
    for (int nt = 0; nt < 4; nt++) {
        float bv = bias[nt * 16 + ln];
        #pragma unroll
        for (int mt = 0; mt < 2; mt++)
            acc[mt][nt] = (f32x4){bv, bv, bv, bv};
    }
    #pragma unroll
    for (int kh = 0; kh < KH; kh++)
        #pragma unroll
        for (int mt = 0; mt < 2; mt++)
            #pragma unroll
            for (int nt = 0; nt < 4; nt++)
                acc[mt][nt] = __builtin_amdgcn_mfma_f32_16x16x32_bf16(
                    afrag[mt][kh], bfrag[nt][kh], acc[mt][nt], 0, 0, 0);

    #pragma unroll
    for (int mt = 0; mt < 2; mt++)
        #pragma unroll
        for (int reg = 0; reg < 4; reg++) {
            int row = nb + rw + mt * 16 + q * 4 + reg;
            if (row < N)
                #pragma unroll
                for (int nt = 0; nt < 4; nt++)
                    out[(size_t)row * 64 + nt * 16 + ln] = bf16_1(acc[mt][nt][reg]);
        }

    // column stats of output
    {
        float s1[4] = {0.f, 0.f, 0.f, 0.f};
        float s2[4] = {0.f, 0.f, 0.f, 0.f};
        #pragma unroll
        for (int mt = 0; mt < 2; mt++)
            #pragma unroll
            for (int reg = 0; reg < 4; reg++) {
                int row = nb + rw + mt * 16 + q * 4 + reg;
                if (row < N)
                    #pragma unroll
                    for (int nt = 0; nt < 4; nt++) {
                        float v = acc[mt][nt][reg];
                        s1[nt] += v;
                        s2[nt] += v * v;
                    }
            }
        #pragma unroll
        for (int nt = 0; nt < 4; nt++) {
            s1[nt] += __shfl_xor(s1[nt], 16);
            s1[nt] += __shfl_xor(s1[nt], 32);
            s2[nt] += __shfl_xor(s2[nt], 16);
            s2[nt] += __shfl_xor(s2[nt], 32);
        }
        __syncthreads();
        if (l < 16) {
            #pragma unroll
            for (int nt = 0; nt < 4; nt++) {
                red[w * 64 + nt * 16 + l]       = s1[nt];
                red[256 + w * 64 + nt * 16 + l] = s2[nt];
            }
        }
        __syncthreads();
        if (tid < 64) {
            float t1 = red[tid] + red[64 + tid] + red[128 + tid] + red[192 + tid];
            float t2 = red[256 + tid] + red[320 + tid] + red[384 + tid] + red[448 + tid];
            unsafeAtomicAdd(&stat_sum[tid],   t1);
            unsafeAtomicAdd(&stat_sumsq[tid], t2);
        }
    }
}

// ---------------------------------------------------------------------------
// Plain MFMA GEMM (encoder INK=1 fp32 input; GEMM2 INK=2 BN+ReLU from stats)
template<int K, int INK, bool STATS>
__global__ __launch_bounds__(256)
void mfma_gemm(const void* __restrict__ Av,
               const float* __restrict__ bn_sum, const float* __restrict__ bn_sumsq,
               const float* __restrict__ gamma, const float* __restrict__ beta,
               float invN,
               const float* __restrict__ W, const float* __restrict__ bias,
               unsigned short* __restrict__ out,
               float* __restrict__ stat_sum, float* __restrict__ stat_sumsq,
               int N)
{
    constexpr int AS  = K + 8;
    constexpr int WS  = K + 8;
    constexpr int CPR = K / 8;
    constexpr int KH  = K / 32;

    __shared__ short a_lds[128 * AS];
    __shared__ short wt_lds[64 * WS];
    __shared__ float ssf[128];
    __shared__ float red[512];

    const int tid = threadIdx.x;
    const int nb  = blockIdx.x * 128;
    const int l   = tid & 63;
    const int w   = tid >> 6;
    const int ln  = l & 15;
    const int q   = l >> 4;

    if (INK == 2) {
        if (tid < 64) {
            float mu  = bn_sum[tid] * invN;
            float var = bn_sumsq[tid] * invN - mu * mu;
            float s   = gamma[tid] * rsqrtf(var + BN_EPS);
            ssf[tid]      = s;
            ssf[64 + tid] = beta[tid] - s * mu;
        }
        __syncthreads();
    }

    for (int idx = tid; idx < K * 64; idx += 256) {
        int k = idx >> 6, n = idx & 63;
        wt_lds[n * WS + k] = (short)bf16_1(W[idx]);
    }

    for (int c = tid; c < 128 * CPR; c += 256) {
        int rloc = c / CPR;
        int j    = c % CPR;
        int row  = nb + rloc;
        uint4 p = make_uint4(0u, 0u, 0u, 0u);
        if (row < N) {
            if (INK == 1) {
                const float4* xr = (const float4*)Av;
                float4 f0 = xr[(size_t)row * (K / 4) + 2 * j];
                float4 f1 = xr[(size_t)row * (K / 4) + 2 * j + 1];
                p.x = pack_bf16x2(f0.x, f0.y); p.y = pack_bf16x2(f0.z, f0.w);
                p.z = pack_bf16x2(f1.x, f1.y); p.w = pack_bf16x2(f1.z, f1.w);
            } else {
                p = ((const uint4*)Av)[(size_t)row * CPR + j];
                if (INK == 2) {
                    int k0 = j * 8;
                    unsigned int* pp = (unsigned int*)&p;
                    #pragma unroll
                    for (int t = 0; t < 4; t++) {
                        float2 f = unpack_bf16x2(pp[t]);
                        int k = k0 + 2 * t;
                        f.x = fmaxf(fmaf(f.x, ssf[k],     ssf[64 + k]),     0.f);
                        f.y = fmaxf(fmaf(f.y, ssf[k + 1], ssf[64 + k + 1]), 0.f);
                        pp[t] = pack_bf16x2(f.x, f.y);
                    }
                }
            }
        }
        *(uint4*)&a_lds[rloc * AS + j * 8] = p;
    }
    __syncthreads();

    short8 afrag[2][KH], bfrag[4][KH];
    const int rw = w * 32;
    #pragma unroll
    for (int mt = 0; mt < 2; mt++)
        #pragma unroll
        for (int kh = 0; kh < KH; kh++)
            afrag[mt][kh] = *(const short8*)&a_lds[(rw + mt * 16 + ln) * AS + kh * 32 + q * 8];
    #pragma unroll
    for (int nt = 0; nt < 4; nt++)
        #pragma unroll
        for (int kh = 0; kh < KH; kh++)
            bfrag[nt][kh] = *(const short8*)&wt_lds[(nt * 16 + ln) * WS + kh * 32 + q * 8];

    f32x4 acc[2][4];
    #pragma unroll
    for (int nt = 0; nt < 4; nt++) {
        float bv = bias[nt * 16 + ln];
        #pragma unroll
        for (int mt = 0; mt < 2; mt++)
            acc[mt][nt] = (f32x4){bv, bv, bv, bv};
    }
    #pragma unroll
    for (int kh = 0; kh < KH; kh++)
        #pragma unroll
        for (int mt = 0; mt < 2; mt++)
            #pragma unroll
            for (int nt = 0; nt < 4; nt++)
                acc[mt][nt] = __builtin_amdgcn_mfma_f32_16x16x32_bf16(
                    afrag[mt][kh], bfrag[nt][kh], acc[mt][nt], 0, 0, 0);

    #pragma unroll
    for (int mt = 0; mt < 2; mt++)
        #pragma unroll
        for (int reg = 0; reg < 4; reg++) {
            int row = nb + rw + mt * 16 + q * 4 + reg;
            if (row < N)
                #pragma unroll
                for (int nt = 0; nt < 4; nt++)
                    out[(size_t)row * 64 + nt * 16 + ln] = bf16_1(acc[mt][nt][reg]);
        }

    if (STATS) {
        float s1[4] = {0.f, 0.f, 0.f, 0.f};
        float s2[4] = {0.f, 0.f, 0.f, 0.f};
        #pragma unroll
        for (int mt = 0; mt < 2; mt++)
            #pragma unroll
            for (int reg = 0; reg < 4; reg++) {
                int row = nb + rw + mt * 16 + q * 4 + reg;
                if (row < N)
                    #pragma unroll
                    for (int nt = 0; nt < 4; nt++) {
                        float v = acc[mt][nt][reg];
                        s1[nt] += v;
                        s2[nt] += v * v;
                    }
            }
        #pragma unroll
        for (int nt = 0; nt < 4; nt++) {
            s1[nt] += __shfl_xor(s1[nt], 16);
            s1[nt] += __shfl_xor(s1[nt], 32);
            s2[nt] += __shfl_xor(s2[nt], 16);
            s2[nt] += __shfl_xor(s2[nt], 32);
        }
        __syncthreads();
        if (l < 16) {
            #pragma unroll
            for (int nt = 0; nt < 4; nt++) {
                red[w * 64 + nt * 16 + l]       = s1[nt];
                red[256 + w * 64 + nt * 16 + l] = s2[nt];
            }
        }
        __syncthreads();
        if (tid < 64) {
            float t1 = red[tid] + red[64 + tid] + red[128 + tid] + red[192 + tid];
            float t2 = red[256 + tid] + red[320 + tid] + red[384 + tid] + red[448 + tid];
            unsafeAtomicAdd(&stat_sum[tid],   t1);
            unsafeAtomicAdd(&stat_sumsq[tid], t2);
        }
    }
}

// ---------------------------------------------------------------------------
// Bucketed edge binning (bucket = dst>>7, <=800 buckets)
__global__ __launch_bounds__(256)
void bucket_hist(const int* __restrict__ dst, int* __restrict__ bhist,
                 int E, int nb)
{
    __shared__ int lh[1024];
    for (int i = threadIdx.x; i < 1024; i += 256) lh[i] = 0;
    __syncthreads();
    for (int e = blockIdx.x * 256 + threadIdx.x; e < E; e += gridDim.x * 256)
        atomicAdd(&lh[dst[e] >> 7], 1);
    __syncthreads();
    for (int i = threadIdx.x; i < nb; i += 256)
        if (lh[i]) atomicAdd(&bhist[i], lh[i]);
}

__global__ __launch_bounds__(1024)
void bucket_scan(const int* __restrict__ bhist, int* __restrict__ bbase,
                 int* __restrict__ bcur, int nb)
{
    __shared__ int sm[1024];
    int t = threadIdx.x;
    int v = (t < nb) ? bhist[t] : 0;
    sm[t] = v; __syncthreads();
    for (int off = 1; off < 1024; off <<= 1) {
        int add = (t >= off) ? sm[t - off] : 0;
        __syncthreads();
        sm[t] += add;
        __syncthreads();
    }
    if (t <= nb) {
        int ex = sm[t] - v;
        bbase[t] = ex;
        if (t < nb) bcur[t * CURS_STRIDE] = ex;
    }
}

__global__ __launch_bounds__(256)
void bucket_scatter(const int* __restrict__ src, const int* __restrict__ dst,
                    int* __restrict__ bcur, int* __restrict__ ebuf,
                    int E, int nb)
{
    constexpr int CH = 4096;
    __shared__ int            key[CH];
    __shared__ unsigned short bid[CH];
    __shared__ int lh[800];
    __shared__ int lbase[800];

    const int t    = threadIdx.x;
    const int base = blockIdx.x * CH;
    const int cnt  = min(CH, E - base);

    for (int i = t; i < nb; i += 256) lh[i] = 0;
    __syncthreads();

    for (int i = t; i < cnt; i += 256) {
        int d = dst[base + i];
        int s = src[base + i];
        int b = d >> 7;
        key[i] = (s << 7) | (d & 127);
        bid[i] = (unsigned short)b;
        atomicAdd(&lh[b], 1);
    }
    __syncthreads();

    for (int i = t; i < nb; i += 256) {
        int c = lh[i];
        if (c) lbase[i] = atomicAdd(&bcur[i * CURS_STRIDE], c);
        lh[i] = 0;
    }
    __syncthreads();

    for (int i = t; i < cnt; i += 256) {
        int b = bid[i];
        int p = atomicAdd(&lh[b], 1);
        ebuf[lbase[b] + p] = key[i];
    }
}

// ---------------------------------------------------------------------------
__global__ __launch_bounds__(256)
void pool_nodes(const unsigned short* __restrict__ hb,
                const float* __restrict__ bsum, const float* __restrict__ bsumsq,
                const float* __restrict__ gamma, const float* __restrict__ beta,
                float invN, const int* __restrict__ batch,
                float* __restrict__ pooled, int N)
{
    int d  = threadIdx.x & 63;
    int nl = threadIdx.x >> 6;
    int nb = blockIdx.x * 32;
    float mu  = bsum[d] * invN;
    float var = bsumsq[d] * invN - mu * mu;
    float s   = gamma[d] * rsqrtf(var + BN_EPS);
    float sh  = beta[d] - s * mu;
    float acc = 0.f;
    int cg = -1;
    #pragma unroll
    for (int r = 0; r < 8; r++) {
        int n = nb + nl * 8 + r;
        if (n >= N) break;
        int g = batch[n];
        if (g != cg) {
            if (cg >= 0) unsafeAtomicAdd(&pooled[(size_t)cg * 64 + d], acc);
            acc = 0.f; cg = g;
        }
        float v = __uint_as_float(((unsigned int)hb[(size_t)n * 64 + d]) << 16);
        acc += fmaxf(fmaf(v, s, sh), 0.f);
    }
    if (cg >= 0) unsafeAtomicAdd(&pooled[(size_t)cg * 64 + d], acc);
}

__global__ __launch_bounds__(256)
void pool_x(const float* __restrict__ x, const int* __restrict__ batch,
            float* __restrict__ px, int N)
{
    int f  = threadIdx.x & 31;
    int nl = threadIdx.x >> 5;
    int nb = blockIdx.x * 64;
    float acc = 0.f;
    int cg = -1;
    #pragma unroll
    for (int r = 0; r < 8; r++) {
        int n = nb + nl * 8 + r;
        if (n >= N) break;
        int g = batch[n];
        if (g != cg) {
            if (cg >= 0) unsafeAtomicAdd(&px[(size_t)cg * 32 + f], acc);
            acc = 0.f; cg = g;
        }
        acc += x[(size_t)n * 32 + f];
    }
    if (cg >= 0) unsafeAtomicAdd(&px[(size_t)cg * 32 + f], acc);
}

// ---------------------------------------------------------------------------
__global__ __launch_bounds__(256)
void head_kernel(const float* __restrict__ px, const float* __restrict__ pl,
                 const float* __restrict__ fcW0, const float* __restrict__ fcb0,
                 const float* __restrict__ fcW, const float* __restrict__ fcb,
                 const int* __restrict__ y, float* __restrict__ out, int G)
{
    int tid = blockIdx.x * 256 + threadIdx.x;
    int total = G * 10;
    if (tid < total) {
        int g = tid / 10, c = tid % 10;
        float acc = fcb0[c];
        const float* pxg = px + (size_t)g * 32;
        #pragma unroll
        for (int k = 0; k < 32; k++) acc = fmaf(pxg[k], fcW0[k * 10 + c], acc);
        #pragma unroll
        for (int i = 0; i < 4; i++) {
            acc += fcb[i * 10 + c];
            const float* pg = pl + ((size_t)i * G + g) * 64;
            const float* w  = fcW + i * 640;
            #pragma unroll
            for (int k = 0; k < 64; k++) acc = fmaf(pg[k], w[k * 10 + c], acc);
        }
        out[tid] = acc;
    } else if (tid < total + G) {
        out[tid] = (float)y[tid - total];
    }
}

// ---------------------------------------------------------------------------
extern "C" void kernel_launch(void* const* d_in, const int* in_sizes, int n_in,
                              void* d_out, int out_size, void* d_ws, size_t ws_size,
                              hipStream_t stream)
{
    const float* x     = (const float*)d_in[0];
    const int*   ei    = (const int*)  d_in[1];
    const int*   batch = (const int*)  d_in[2];
    const int*   y     = (const int*)  d_in[3];
    const float* W_enc = (const float*)d_in[4];
    const float* b_enc = (const float*)d_in[5];
    const float* W1    = (const float*)d_in[6];
    const float* b1    = (const float*)d_in[7];
    const float* g1    = (const float*)d_in[8];
    const float* be1   = (const float*)d_in[9];
    const float* W2    = (const float*)d_in[10];
    const float* b2    = (const float*)d_in[11];
    const float* gout  = (const float*)d_in[12];
    const float* bout  = (const float*)d_in[13];
    const float* fcW0  = (const float*)d_in[14];
    const float* fcb0  = (const float*)d_in[15];
    const float* fcW   = (const float*)d_in[16];
    const float* fcb   = (const float*)d_in[17];

    const int N = in_sizes[0] / 32;   // 100000
    const int E = in_sizes[1] / 2;    // 1600000
    const int G = in_sizes[3];        // 2000
    const int* src = ei;
    const int* dst = ei + E;
    const int NB = (N + 127) / 128;   // 782 buckets

    // ws layout: m bf16 | hb bf16 | stats | px | pl | bbase | ebuf
    unsigned int* m  = (unsigned int*)d_ws;          // N*32 uints
    unsigned int* hb = m + (size_t)N * 32;           // N*32 uints
    float* stats = (float*)(hb + (size_t)N * 32);    // [4][2] x 128
    float* px    = stats + 1024;                     // G*32
    float* pl    = px + (size_t)G * 32;              // 4*G*64
    int*   bbase = (int*)(pl + (size_t)4 * G * 64);  // NB+1 (<=1024)
    int*   ebuf  = bbase + 1024;                     // E
    // build temps alias m (dead before layer-0 gin_gemm1 writes m)
    int*   mi    = (int*)m;
    int*   bhist = mi;
    int*   bcur  = mi + 1024;

    size_t zbytes = (size_t)(1024 + G * 32 + 4 * G * 64) * sizeof(float);
    hipMemsetAsync(stats, 0, zbytes, stream);
    hipMemsetAsync(bhist, 0, 1024 * sizeof(int), stream);

    // bucketed edge binning (ebuf consumed directly by gin_gemm1)
    bucket_hist<<<160, 256, 0, stream>>>(dst, bhist, E, NB);
    bucket_scan<<<1, 1024, 0, stream>>>(bhist, bbase, bcur, NB);
    bucket_scatter<<<(E + 4095) / 4096, 256, 0, stream>>>(src, dst, bcur, ebuf, E, NB);

    const int gb = NB;
    const float invN = 1.0f / (float)N;

    // encoder: hb = bf16(x @ W_enc + b_enc)
    mfma_gemm<32, 1, false><<<gb, 256, 0, stream>>>(
        x, nullptr, nullptr, nullptr, nullptr, 0.f,
        W_enc, b_enc, (unsigned short*)hb, nullptr, nullptr, N);
    pool_x<<<(N + 63) / 64, 256, 0, stream>>>(x, batch, px, N);

    for (int i = 0; i < 4; i++) {
        float* s1a = stats + (i * 2 + 0) * 128;
        float* s1b = s1a + 64;
        float* s2a = stats + (i * 2 + 1) * 128;
        float* s2b = s2a + 64;

        // m = bf16( (t(hb[n]) + sum t(hb[nbr])) @ W1 + b1 ) + stats s1 (fused)
        if (i == 0) {
            gin_gemm1<false><<<gb, 256, 0, stream>>>(
                bbase, ebuf, hb, nullptr, nullptr, nullptr, nullptr, 0.f,
                W1 + (size_t)i * 4096, b1 + i * 64, (unsigned short*)m, s1a, s1b, N);
        } else {
            float* p2a = stats + ((i - 1) * 2 + 1) * 128;
            float* p2b = p2a + 64;
            gin_gemm1<true><<<gb, 256, 0, stream>>>(
                bbase, ebuf, hb, p2a, p2b,
                gout + (i - 1) * 64, bout + (i - 1) * 64, invN,
                W1 + (size_t)i * 4096, b1 + i * 64, (unsigned short*)m, s1a, s1b, N);
        }

        // hb = bf16( relu(bn1(m)) @ W2[i] + b2[i] ) + stats s2
        mfma_gemm<64, 2, true><<<gb, 256, 0, stream>>>(
            m, s1a, s1b, g1 + i * 64, be1 + i * 64, invN,
            W2 + (size_t)i * 4096, b2 + i * 64, (unsigned short*)hb, s2a, s2b, N);

        // pl[i][g] += relu(bn2(hb))
        pool_nodes<<<(N + 31) / 32, 256, 0, stream>>>(
            (const unsigned short*)hb, s2a, s2b, gout + i * 64, bout + i * 64, invN,
            batch, pl + (size_t)i * G * 64, N);
    }

    head_kernel<<<(G * 10 + G + 255) / 256, 256, 0, stream>>>(
        px, pl, fcW0, fcb0, fcW, fcb, y, (float*)d_out, G);
}

// Round 10
// 634.304 us; speedup vs baseline: 4.7755x; 4.7755x over previous
//
#include <hip/hip_runtime.h>

// GIN round 10: revert to round-8 row-parallel fused gather (round-9 LDS-atomic
// edge-parallel was 12x slower — ds atomics serialize). New: BN+ReLU applied
// once per layer in a streaming bn_pool pass (writes hb in place + JK pooling),
// so the gather is a pure bf16 sum (VALU per load halved), 8-deep unroll.

#define BN_EPS 1e-5f
#define CURS_STRIDE 16

typedef __attribute__((ext_vector_type(8))) short short8;
typedef __attribute__((ext_vector_type(4))) float f32x4;

// ---- bf16 helpers (rne) ----
__device__ __forceinline__ unsigned int pack_bf16x2(float a, float b) {
    unsigned int ua = __float_as_uint(a);
    unsigned int ub = __float_as_uint(b);
    ua = (ua + 0x7FFFu + ((ua >> 16) & 1u)) >> 16;
    ub = (ub + 0x7FFFu + ((ub >> 16) & 1u)) >> 16;
    return ua | (ub << 16);
}
__device__ __forceinline__ unsigned short bf16_1(float f) {
    unsigned int u = __float_as_uint(f);
    u = (u + 0x7FFFu + ((u >> 16) & 1u)) >> 16;
    return (unsigned short)u;
}
__device__ __forceinline__ float2 unpack_bf16x2(unsigned int u) {
    float2 r;
    r.x = __uint_as_float(u << 16);
    r.y = __uint_as_float(u & 0xFFFF0000u);
    return r;
}

__device__ __forceinline__ void acc_row8(float (&acc)[8], uint4 p) {
    unsigned int pp[4] = {p.x, p.y, p.z, p.w};
    #pragma unroll
    for (int t = 0; t < 4; t++) {
        float2 f = unpack_bf16x2(pp[t]);
        acc[2 * t]     += f.x;
        acc[2 * t + 1] += f.y;
    }
}

// ---------------------------------------------------------------------------
// Fused GIN stage 1: A[n] = hb[n] + sum_{s in nbrs(n)} hb[s]  (hb already
// BN+ReLU'd by bn_pool, or raw encoder output for layer 0).
// out = bf16(A @ W1 + b1), column stats -> s1.
__global__ __launch_bounds__(256)
void gin_gemm1(const int* __restrict__ rowp, const int* __restrict__ srcs,
               const unsigned int* __restrict__ hb,
               const float* __restrict__ W, const float* __restrict__ bias,
               unsigned short* __restrict__ out,
               float* __restrict__ stat_sum, float* __restrict__ stat_sumsq,
               int N)
{
    constexpr int AS = 72, WS = 72, KH = 2;
    __shared__ short a_lds[128 * AS];
    __shared__ short wt_lds[64 * WS];
    __shared__ float red[512];

    const int tid = threadIdx.x;
    const int nb  = blockIdx.x * 128;
    const int l   = tid & 63;
    const int w   = tid >> 6;
    const int ln  = l & 15;
    const int q   = l >> 4;

    // stage W^T bf16
    for (int idx = tid; idx < 64 * 64; idx += 256) {
        int k = idx >> 6, n = idx & 63;
        wt_lds[n * WS + k] = (short)bf16_1(W[idx]);
    }

    // gather A-tile: 8 lanes/row, uint4 (8 bf16) per lane, 8-deep unroll
    const uint4* hb4 = (const uint4*)hb;
    const int cc = tid & 7;
    const int rl = tid >> 3;
    for (int it = 0; it < 4; it++) {
        int rloc = it * 32 + rl;
        int n = nb + rloc;
        float acc[8] = {0.f, 0.f, 0.f, 0.f, 0.f, 0.f, 0.f, 0.f};
        if (n < N) {
            acc_row8(acc, hb4[(size_t)n * 8 + cc]);
            int e = rowp[n], end = rowp[n + 1];
            for (; e + 7 < end; e += 8) {
                uint4 p[8];
                #pragma unroll
                for (int j = 0; j < 8; j++)
                    p[j] = hb4[(size_t)srcs[e + j] * 8 + cc];
                #pragma unroll
                for (int j = 0; j < 8; j++)
                    acc_row8(acc, p[j]);
            }
            for (; e + 1 < end; e += 2) {
                uint4 p0 = hb4[(size_t)srcs[e] * 8 + cc];
                uint4 p1 = hb4[(size_t)srcs[e + 1] * 8 + cc];
                acc_row8(acc, p0);
                acc_row8(acc, p1);
            }
            if (e < end)
                acc_row8(acc, hb4[(size_t)srcs[e] * 8 + cc]);
        }
        uint4 o;
        o.x = pack_bf16x2(acc[0], acc[1]);
        o.y = pack_bf16x2(acc[2], acc[3]);
        o.z = pack_bf16x2(acc[4], acc[5]);
        o.w = pack_bf16x2(acc[6], acc[7]);
        *(uint4*)&a_lds[rloc * AS + cc * 8] = o;
    }
    __syncthreads();

    short8 afrag[2][KH], bfrag[4][KH];
    const int rw = w * 32;
    #pragma unroll
    for (int mt = 0; mt < 2; mt++)
        #pragma unroll
        for (int kh = 0; kh < KH; kh++)
            afrag[mt][kh] = *(const short8*)&a_lds[(rw + mt * 16 + ln) * AS + kh * 32 + q * 8];
    #pragma unroll
    for (int nt = 0; nt < 4; nt++)
        #pragma unroll
        for (int kh = 0; kh < KH; kh++)
            bfrag[nt][kh] = *(const short8*)&wt_lds[(nt * 16 + ln) * WS + kh * 32 + q * 8];

    f32x4 acc[2][4];
    #pragma unroll
    for (int nt = 0; nt < 4; nt++) {
        float bv = bias[nt * 16 + ln];
        #pragma unroll
        for (int mt = 0; mt < 2; mt++)
            acc[mt][nt] = (f32x4){bv, bv, bv, bv};
    }
    #pragma unroll
    for (int kh = 0; kh < KH; kh++)
        #pragma unroll
        for (int mt = 0; mt < 2; mt++)
            #pragma unroll
            for (int nt = 0; nt < 4; nt++)
                acc[mt][nt] = __builtin_amdgcn_mfma_f32_16x16x32_bf16(
                    afrag[mt][kh], bfrag[nt][kh], acc[mt][nt], 0, 0, 0);

    #pragma unroll
    for (int mt = 0; mt < 2; mt++)
        #pragma unroll
        for (int reg = 0; reg < 4; reg++) {
            int row = nb + rw + mt * 16 + q * 4 + reg;
            if (row < N)
                #pragma unroll
                for (int nt = 0; nt < 4; nt++)
                    out[(size_t)row * 64 + nt * 16 + ln] = bf16_1(acc[mt][nt][reg]);
        }

    // column stats of output
    {
        float s1[4] = {0.f, 0.f, 0.f, 0.f};
        float s2[4] = {0.f, 0.f, 0.f, 0.f};
        #pragma unroll
        for (int mt = 0; mt < 2; mt++)
            #pragma unroll
            for (int reg = 0; reg < 4; reg++) {
                int row = nb + rw + mt * 16 + q * 4 + reg;
                if (row < N)
                    #pragma unroll
                    for (int nt = 0; nt < 4; nt++) {
                        float v = acc[mt][nt][reg];
                        s1[nt] += v;
                        s2[nt] += v * v;
                    }
            }
        #pragma unroll
        for (int nt = 0; nt < 4; nt++) {
            s1[nt] += __shfl_xor(s1[nt], 16);
            s1[nt] += __shfl_xor(s1[nt], 32);
            s2[nt] += __shfl_xor(s2[nt], 16);
            s2[nt] += __shfl_xor(s2[nt], 32);
        }
        __syncthreads();
        if (l < 16) {
            #pragma unroll
            for (int nt = 0; nt < 4; nt++) {
                red[w * 64 + nt * 16 + l]       = s1[nt];
                red[256 + w * 64 + nt * 16 + l] = s2[nt];
            }
        }
        __syncthreads();
        if (tid < 64) {
            float t1 = red[tid] + red[64 + tid] + red[128 + tid] + red[192 + tid];
            float t2 = red[256 + tid] + red[320 + tid] + red[384 + tid] + red[448 + tid];
            unsafeAtomicAdd(&stat_sum[tid],   t1);
            unsafeAtomicAdd(&stat_sumsq[tid], t2);
        }
    }
}

// ---------------------------------------------------------------------------
// Plain MFMA GEMM (encoder INK=1 fp32 input; GEMM2 INK=2 BN+ReLU from stats)
template<int K, int INK, bool STATS>
__global__ __launch_bounds__(256)
void mfma_gemm(const void* __restrict__ Av,
               const float* __restrict__ bn_sum, const float* __restrict__ bn_sumsq,
               const float* __restrict__ gamma, const float* __restrict__ beta,
               float invN,
               const float* __restrict__ W, const float* __restrict__ bias,
               unsigned short* __restrict__ out,
               float* __restrict__ stat_sum, float* __restrict__ stat_sumsq,
               int N)
{
    constexpr int AS  = K + 8;
    constexpr int WS  = K + 8;
    constexpr int CPR = K / 8;
    constexpr int KH  = K / 32;

    __shared__ short a_lds[128 * AS];
    __shared__ short wt_lds[64 * WS];
    __shared__ float ssf[128];
    __shared__ float red[512];

    const int tid = threadIdx.x;
    const int nb  = blockIdx.x * 128;
    const int l   = tid & 63;
    const int w   = tid >> 6;
    const int ln  = l & 15;
    const int q   = l >> 4;

    if (INK == 2) {
        if (tid < 64) {
            float mu  = bn_sum[tid] * invN;
            float var = bn_sumsq[tid] * invN - mu * mu;
            float s   = gamma[tid] * rsqrtf(var + BN_EPS);
            ssf[tid]      = s;
            ssf[64 + tid] = beta[tid] - s * mu;
        }
        __syncthreads();
    }

    for (int idx = tid; idx < K * 64; idx += 256) {
        int k = idx >> 6, n = idx & 63;
        wt_lds[n * WS + k] = (short)bf16_1(W[idx]);
    }

    for (int c = tid; c < 128 * CPR; c += 256) {
        int rloc = c / CPR;
        int j    = c % CPR;
        int row  = nb + rloc;
        uint4 p = make_uint4(0u, 0u, 0u, 0u);
        if (row < N) {
            if (INK == 1) {
                const float4* xr = (const float4*)Av;
                float4 f0 = xr[(size_t)row * (K / 4) + 2 * j];
                float4 f1 = xr[(size_t)row * (K / 4) + 2 * j + 1];
                p.x = pack_bf16x2(f0.x, f0.y); p.y = pack_bf16x2(f0.z, f0.w);
                p.z = pack_bf16x2(f1.x, f1.y); p.w = pack_bf16x2(f1.z, f1.w);
            } else {
                p = ((const uint4*)Av)[(size_t)row * CPR + j];
                if (INK == 2) {
                    int k0 = j * 8;
                    unsigned int* pp = (unsigned int*)&p;
                    #pragma unroll
                    for (int t = 0; t < 4; t++) {
                        float2 f = unpack_bf16x2(pp[t]);
                        int k = k0 + 2 * t;
                        f.x = fmaxf(fmaf(f.x, ssf[k],     ssf[64 + k]),     0.f);
                        f.y = fmaxf(fmaf(f.y, ssf[k + 1], ssf[64 + k + 1]), 0.f);
                        pp[t] = pack_bf16x2(f.x, f.y);
                    }
                }
            }
        }
        *(uint4*)&a_lds[rloc * AS + j * 8] = p;
    }
    __syncthreads();

    short8 afrag[2][KH], bfrag[4][KH];
    const int rw = w * 32;
    #pragma unroll
    for (int mt = 0; mt < 2; mt++)
        #pragma unroll
        for (int kh = 0; kh < KH; kh++)
            afrag[mt][kh] = *(const short8*)&a_lds[(rw + mt * 16 + ln) * AS + kh * 32 + q * 8];
    #pragma unroll
    for (int nt = 0; nt < 4; nt++)
        #pragma unroll
        for (int kh = 0; kh < KH; kh++)
            bfrag[nt][kh] = *(const short8*)&wt_lds[(nt * 16 + ln) * WS + kh * 32 + q * 8];

    f32x4 acc[2][4];
    #pragma unroll
    for (int nt = 0; nt < 4; nt++) {
        float bv = bias[nt * 16 + ln];
        #pragma unroll
        for (int mt = 0; mt < 2; mt++)
            acc[mt][nt] = (f32x4){bv, bv, bv, bv};
    }
    #pragma unroll
    for (int kh = 0; kh < KH; kh++)
        #pragma unroll
        for (int mt = 0; mt < 2; mt++)
            #pragma unroll
            for (int nt = 0; nt < 4; nt++)
                acc[mt][nt] = __builtin_amdgcn_mfma_f32_16x16x32_bf16(
                    afrag[mt][kh], bfrag[nt][kh], acc[mt][nt], 0, 0, 0);

    #pragma unroll
    for (int mt = 0; mt < 2; mt++)
        #pragma unroll
        for (int reg = 0; reg < 4; reg++) {
            int row = nb + rw + mt * 16 + q * 4 + reg;
            if (row < N)
                #pragma unroll
                for (int nt = 0; nt < 4; nt++)
                    out[(size_t)row * 64 + nt * 16 + ln] = bf16_1(acc[mt][nt][reg]);
        }

    if (STATS) {
        float s1[4] = {0.f, 0.f, 0.f, 0.f};
        float s2[4] = {0.f, 0.f, 0.f, 0.f};
        #pragma unroll
        for (int mt = 0; mt < 2; mt++)
            #pragma unroll
            for (int reg = 0; reg < 4; reg++) {
                int row = nb + rw + mt * 16 + q * 4 + reg;
                if (row < N)
                    #pragma unroll
                    for (int nt = 0; nt < 4; nt++) {
                        float v = acc[mt][nt][reg];
                        s1[nt] += v;
                        s2[nt] += v * v;
                    }
            }
        #pragma unroll
        for (int nt = 0; nt < 4; nt++) {
            s1[nt] += __shfl_xor(s1[nt], 16);
            s1[nt] += __shfl_xor(s1[nt], 32);
            s2[nt] += __shfl_xor(s2[nt], 16);
            s2[nt] += __shfl_xor(s2[nt], 32);
        }
        __syncthreads();
        if (l < 16) {
            #pragma unroll
            for (int nt = 0; nt < 4; nt++) {
                red[w * 64 + nt * 16 + l]       = s1[nt];
                red[256 + w * 64 + nt * 16 + l] = s2[nt];
            }
        }
        __syncthreads();
        if (tid < 64) {
            float t1 = red[tid] + red[64 + tid] + red[128 + tid] + red[192 + tid];
            float t2 = red[256 + tid] + red[320 + tid] + red[384 + tid] + red[448 + tid];
            unsafeAtomicAdd(&stat_sum[tid],   t1);
            unsafeAtomicAdd(&stat_sumsq[tid], t2);
        }
    }
}

// ---------------------------------------------------------------------------
// Bucketed CSR build (bucket = dst>>7, <=800 buckets)
__global__ __launch_bounds__(256)
void bucket_hist(const int* __restrict__ dst, int* __restrict__ bhist,
                 int E, int nb)
{
    __shared__ int lh[1024];
    for (int i = threadIdx.x; i < 1024; i += 256) lh[i] = 0;
    __syncthreads();
    for (int e = blockIdx.x * 256 + threadIdx.x; e < E; e += gridDim.x * 256)
        atomicAdd(&lh[dst[e] >> 7], 1);
    __syncthreads();
    for (int i = threadIdx.x; i < nb; i += 256)
        if (lh[i]) atomicAdd(&bhist[i], lh[i]);
}

__global__ __launch_bounds__(1024)
void bucket_scan(const int* __restrict__ bhist, int* __restrict__ bbase,
                 int* __restrict__ bcur, int nb)
{
    __shared__ int sm[1024];
    int t = threadIdx.x;
    int v = (t < nb) ? bhist[t] : 0;
    sm[t] = v; __syncthreads();
    for (int off = 1; off < 1024; off <<= 1) {
        int add = (t >= off) ? sm[t - off] : 0;
        __syncthreads();
        sm[t] += add;
        __syncthreads();
    }
    if (t <= nb) {
        int ex = sm[t] - v;
        bbase[t] = ex;
        if (t < nb) bcur[t * CURS_STRIDE] = ex;
    }
}

__global__ __launch_bounds__(256)
void bucket_scatter(const int* __restrict__ src, const int* __restrict__ dst,
                    int* __restrict__ bcur, int* __restrict__ ebuf,
                    int E, int nb)
{
    constexpr int CH = 4096;
    __shared__ int            key[CH];
    __shared__ unsigned short bid[CH];
    __shared__ int lh[800];
    __shared__ int lbase[800];

    const int t    = threadIdx.x;
    const int base = blockIdx.x * CH;
    const int cnt  = min(CH, E - base);

    for (int i = t; i < nb; i += 256) lh[i] = 0;
    __syncthreads();

    for (int i = t; i < cnt; i += 256) {
        int d = dst[base + i];
        int s = src[base + i];
        int b = d >> 7;
        key[i] = (s << 7) | (d & 127);
        bid[i] = (unsigned short)b;
        atomicAdd(&lh[b], 1);
    }
    __syncthreads();

    for (int i = t; i < nb; i += 256) {
        int c = lh[i];
        if (c) lbase[i] = atomicAdd(&bcur[i * CURS_STRIDE], c);
        lh[i] = 0;
    }
    __syncthreads();

    for (int i = t; i < cnt; i += 256) {
        int b = bid[i];
        int p = atomicAdd(&lh[b], 1);
        ebuf[lbase[b] + p] = key[i];
    }
}

__global__ __launch_bounds__(256)
void bucket_csr(const int* __restrict__ bbase, const int* __restrict__ ebuf,
                int* __restrict__ row, int* __restrict__ srcs, int N, int E)
{
    __shared__ int lh[128], lofs[128], lcur[128];
    const int b   = blockIdx.x;
    const int tid = threadIdx.x;
    const int beg = bbase[b], end = bbase[b + 1];

    if (tid < 128) lh[tid] = 0;
    __syncthreads();
    for (int e = beg + tid; e < end; e += 256)
        atomicAdd(&lh[ebuf[e] & 127], 1);
    __syncthreads();

    int v = (tid < 128) ? lh[tid] : 0;
    if (tid < 128) lofs[tid] = v;
    __syncthreads();
    for (int off = 1; off < 128; off <<= 1) {
        int add = 0;
        if (tid < 128 && tid >= off) add = lofs[tid - off];
        __syncthreads();
        if (tid < 128) lofs[tid] += add;
        __syncthreads();
    }
    if (tid < 128) {
        int ex = lofs[tid] - v;
        lcur[tid] = ex;
        int node = b * 128 + tid;
        if (node < N) row[node] = beg + ex;
    }
    if (b == 0 && tid == 0) row[N] = E;
    __syncthreads();

    for (int e = beg + tid; e < end; e += 256) {
        int pk = ebuf[e];
        int p = atomicAdd(&lcur[pk & 127], 1);
        srcs[beg + p] = pk >> 7;
    }
}

// ---------------------------------------------------------------------------
// hb = bf16(relu(bn(hb))) in place (scale/shift from raw stats) + JK pooling.
// 2 columns per thread (uint), run-length pooling over sorted batch ids.
__global__ __launch_bounds__(256)
void bn_pool(unsigned int* __restrict__ hb,
             const float* __restrict__ bsum, const float* __restrict__ bsumsq,
             const float* __restrict__ gamma, const float* __restrict__ beta,
             float invN, const int* __restrict__ batch,
             float* __restrict__ pooled, int N)
{
    int d2 = threadIdx.x & 31;       // uint index: cols 2*d2, 2*d2+1
    int nl = threadIdx.x >> 5;       // 0..7
    int nb = blockIdx.x * 64;
    int c0 = 2 * d2, c1 = c0 + 1;
    float mu0 = bsum[c0] * invN, mu1 = bsum[c1] * invN;
    float s0 = gamma[c0] * rsqrtf(bsumsq[c0] * invN - mu0 * mu0 + BN_EPS);
    float s1 = gamma[c1] * rsqrtf(bsumsq[c1] * invN - mu1 * mu1 + BN_EPS);
    float h0 = beta[c0] - s0 * mu0, h1 = beta[c1] - s1 * mu1;
    float a0 = 0.f, a1 = 0.f;
    int cg = -1;
    #pragma unroll
    for (int r = 0; r < 8; r++) {
        int n = nb + nl * 8 + r;
        if (n >= N) break;
        int g = batch[n];
        if (g != cg) {
            if (cg >= 0) {
                unsafeAtomicAdd(&pooled[(size_t)cg * 64 + c0], a0);
                unsafeAtomicAdd(&pooled[(size_t)cg * 64 + c1], a1);
            }
            a0 = a1 = 0.f; cg = g;
        }
        unsigned int u = hb[(size_t)n * 32 + d2];
        float2 f = unpack_bf16x2(u);
        f.x = fmaxf(fmaf(f.x, s0, h0), 0.f);
        f.y = fmaxf(fmaf(f.y, s1, h1), 0.f);
        hb[(size_t)n * 32 + d2] = pack_bf16x2(f.x, f.y);
        a0 += f.x; a1 += f.y;
    }
    if (cg >= 0) {
        unsafeAtomicAdd(&pooled[(size_t)cg * 64 + c0], a0);
        unsafeAtomicAdd(&pooled[(size_t)cg * 64 + c1], a1);
    }
}

__global__ __launch_bounds__(256)
void pool_x(const float* __restrict__ x, const int* __restrict__ batch,
            float* __restrict__ px, int N)
{
    int f  = threadIdx.x & 31;
    int nl = threadIdx.x >> 5;
    int nb = blockIdx.x * 64;
    float acc = 0.f;
    int cg = -1;
    #pragma unroll
    for (int r = 0; r < 8; r++) {
        int n = nb + nl * 8 + r;
        if (n >= N) break;
        int g = batch[n];
        if (g != cg) {
            if (cg >= 0) unsafeAtomicAdd(&px[(size_t)cg * 32 + f], acc);
            acc = 0.f; cg = g;
        }
        acc += x[(size_t)n * 32 + f];
    }
    if (cg >= 0) unsafeAtomicAdd(&px[(size_t)cg * 32 + f], acc);
}

// ---------------------------------------------------------------------------
__global__ __launch_bounds__(256)
void head_kernel(const float* __restrict__ px, const float* __restrict__ pl,
                 const float* __restrict__ fcW0, const float* __restrict__ fcb0,
                 const float* __restrict__ fcW, const float* __restrict__ fcb,
                 const int* __restrict__ y, float* __restrict__ out, int G)
{
    int tid = blockIdx.x * 256 + threadIdx.x;
    int total = G * 10;
    if (tid < total) {
        int g = tid / 10, c = tid % 10;
        float acc = fcb0[c];
        const float* pxg = px + (size_t)g * 32;
        #pragma unroll
        for (int k = 0; k < 32; k++) acc = fmaf(pxg[k], fcW0[k * 10 + c], acc);
        #pragma unroll
        for (int i = 0; i < 4; i++) {
            acc += fcb[i * 10 + c];
            const float* pg = pl + ((size_t)i * G + g) * 64;
            const float* w  = fcW + i * 640;
            #pragma unroll
            for (int k = 0; k < 64; k++) acc = fmaf(pg[k], w[k * 10 + c], acc);
        }
        out[tid] = acc;
    } else if (tid < total + G) {
        out[tid] = (float)y[tid - total];
    }
}

// ---------------------------------------------------------------------------
extern "C" void kernel_launch(void* const* d_in, const int* in_sizes, int n_in,
                              void* d_out, int out_size, void* d_ws, size_t ws_size,
                              hipStream_t stream)
{
    const float* x     = (const float*)d_in[0];
    const int*   ei    = (const int*)  d_in[1];
    const int*   batch = (const int*)  d_in[2];
    const int*   y     = (const int*)  d_in[3];
    const float* W_enc = (const float*)d_in[4];
    const float* b_enc = (const float*)d_in[5];
    const float* W1    = (const float*)d_in[6];
    const float* b1    = (const float*)d_in[7];
    const float* g1    = (const float*)d_in[8];
    const float* be1   = (const float*)d_in[9];
    const float* W2    = (const float*)d_in[10];
    const float* b2    = (const float*)d_in[11];
    const float* gout  = (const float*)d_in[12];
    const float* bout  = (const float*)d_in[13];
    const float* fcW0  = (const float*)d_in[14];
    const float* fcb0  = (const float*)d_in[15];
    const float* fcW   = (const float*)d_in[16];
    const float* fcb   = (const float*)d_in[17];

    const int N = in_sizes[0] / 32;   // 100000
    const int E = in_sizes[1] / 2;    // 1600000
    const int G = in_sizes[3];        // 2000
    const int* src = ei;
    const int* dst = ei + E;
    const int NB = (N + 127) / 128;   // 782 buckets

    // ws layout: m bf16 | hb bf16 | stats | px | pl | row | srcs
    unsigned int* m  = (unsigned int*)d_ws;          // N*32 uints
    unsigned int* hb = m + (size_t)N * 32;           // N*32 uints
    float* stats = (float*)(hb + (size_t)N * 32);    // [4][2] x 128
    float* px    = stats + 1024;                     // G*32
    float* pl    = px + (size_t)G * 32;              // 4*G*64
    int*   row   = (int*)(pl + (size_t)4 * G * 64);  // N+1
    int*   srcs  = row + (N + 1);                    // E
    // CSR temps alias m (dead before layer-0 gin_gemm1 writes m)
    int*   mi    = (int*)m;
    int*   bhist = mi;
    int*   bbase = mi + 1024;
    int*   bcur  = mi + 2048;
    int*   ebuf  = mi + 2048 + 800 * CURS_STRIDE;

    size_t zbytes = (size_t)(1024 + G * 32 + 4 * G * 64) * sizeof(float);
    hipMemsetAsync(stats, 0, zbytes, stream);
    hipMemsetAsync(bhist, 0, 1024 * sizeof(int), stream);

    // bucketed CSR build
    bucket_hist<<<160, 256, 0, stream>>>(dst, bhist, E, NB);
    bucket_scan<<<1, 1024, 0, stream>>>(bhist, bbase, bcur, NB);
    bucket_scatter<<<(E + 4095) / 4096, 256, 0, stream>>>(src, dst, bcur, ebuf, E, NB);
    bucket_csr<<<NB, 256, 0, stream>>>(bbase, ebuf, row, srcs, N, E);

    const int gb = NB;
    const float invN = 1.0f / (float)N;

    // encoder: hb = bf16(x @ W_enc + b_enc)   (raw; layer-0 gather uses as-is)
    mfma_gemm<32, 1, false><<<gb, 256, 0, stream>>>(
        x, nullptr, nullptr, nullptr, nullptr, 0.f,
        W_enc, b_enc, (unsigned short*)hb, nullptr, nullptr, N);
    pool_x<<<(N + 63) / 64, 256, 0, stream>>>(x, batch, px, N);

    for (int i = 0; i < 4; i++) {
        float* s1a = stats + (i * 2 + 0) * 128;
        float* s1b = s1a + 64;
        float* s2a = stats + (i * 2 + 1) * 128;
        float* s2b = s2a + 64;

        // m = bf16( (hb[n] + sum hb[nbr]) @ W1 + b1 ) + stats s1  (BN-free gather)
        gin_gemm1<<<gb, 256, 0, stream>>>(
            row, srcs, hb, W1 + (size_t)i * 4096, b1 + i * 64,
            (unsigned short*)m, s1a, s1b, N);

        // hb = bf16( relu(bn1(m)) @ W2[i] + b2[i] ) + stats s2
        mfma_gemm<64, 2, true><<<gb, 256, 0, stream>>>(
            m, s1a, s1b, g1 + i * 64, be1 + i * 64, invN,
            W2 + (size_t)i * 4096, b2 + i * 64, (unsigned short*)hb, s2a, s2b, N);

        // hb = relu(bn2(hb)) in place; pl[i][g] += hb
        bn_pool<<<(N + 63) / 64, 256, 0, stream>>>(
            hb, s2a, s2b, gout + i * 64, bout + i * 64, invN,
            batch, pl + (size_t)i * G * 64, N);
    }

    head_kernel<<<(G * 10 + G + 255) / 256, 256, 0, stream>>>(
        px, pl, fcW0, fcb0, fcW, fcb, y, (float*)d_out, G);
}

// Round 11
// 617.031 us; speedup vs baseline: 4.9091x; 1.0280x over previous
//
#include <hip/hip_runtime.h>

// GIN round 11: round-8 structure restored (BN fused in gather, 4-deep unroll,
// pool_nodes with BN) + gin_gemm1 moved to 64-row tiles: 1563 blocks, ~21 KB
// LDS -> ~6 blocks/CU resident (was 3), doubling gather loads-in-flight.

#define BN_EPS 1e-5f
#define CURS_STRIDE 16

typedef __attribute__((ext_vector_type(8))) short short8;
typedef __attribute__((ext_vector_type(4))) float f32x4;

// ---- bf16 helpers (rne) ----
__device__ __forceinline__ unsigned int pack_bf16x2(float a, float b) {
    unsigned int ua = __float_as_uint(a);
    unsigned int ub = __float_as_uint(b);
    ua = (ua + 0x7FFFu + ((ua >> 16) & 1u)) >> 16;
    ub = (ub + 0x7FFFu + ((ub >> 16) & 1u)) >> 16;
    return ua | (ub << 16);
}
__device__ __forceinline__ unsigned short bf16_1(float f) {
    unsigned int u = __float_as_uint(f);
    u = (u + 0x7FFFu + ((u >> 16) & 1u)) >> 16;
    return (unsigned short)u;
}
__device__ __forceinline__ float2 unpack_bf16x2(unsigned int u) {
    float2 r;
    r.x = __uint_as_float(u << 16);
    r.y = __uint_as_float(u & 0xFFFF0000u);
    return r;
}

template<bool BN>
__device__ __forceinline__ void acc_row8(float (&acc)[8], uint4 p,
                                         const float* sc, const float* sh) {
    unsigned int pp[4] = {p.x, p.y, p.z, p.w};
    #pragma unroll
    for (int t = 0; t < 4; t++) {
        float2 f = unpack_bf16x2(pp[t]);
        if (BN) {
            f.x = fmaxf(fmaf(f.x, sc[2 * t],     sh[2 * t]),     0.f);
            f.y = fmaxf(fmaf(f.y, sc[2 * t + 1], sh[2 * t + 1]), 0.f);
        }
        acc[2 * t]     += f.x;
        acc[2 * t + 1] += f.y;
    }
}

// ---------------------------------------------------------------------------
// Fused GIN conv stage 1 (64-row tile): A[n] = t(hb[n]) + sum t(hb[nbr]),
// out = bf16(A @ W1 + b1), column stats -> s1. t = BN?relu(v*s+sh):v.
// Block 256 thr / 4 waves; wave w computes rows [w*16, w*16+16).
template<bool BN>
__global__ __launch_bounds__(256)
void gin_gemm1(const int* __restrict__ rowp, const int* __restrict__ srcs,
               const unsigned int* __restrict__ hb,
               const float* __restrict__ bsum, const float* __restrict__ bsumsq,
               const float* __restrict__ gamma, const float* __restrict__ beta,
               float invN,
               const float* __restrict__ W, const float* __restrict__ bias,
               unsigned short* __restrict__ out,
               float* __restrict__ stat_sum, float* __restrict__ stat_sumsq,
               int N)
{
    constexpr int AS = 72, WS = 72, KH = 2;
    __shared__ short a_lds[64 * AS];
    __shared__ short wt_lds[64 * WS];
    __shared__ float ssf[128];
    __shared__ float red[512];

    const int tid = threadIdx.x;
    const int nb  = blockIdx.x * 64;
    const int l   = tid & 63;
    const int w   = tid >> 6;
    const int ln  = l & 15;
    const int q   = l >> 4;

    if (BN) {
        if (tid < 64) {
            float mu  = bsum[tid] * invN;
            float var = bsumsq[tid] * invN - mu * mu;
            float s   = gamma[tid] * rsqrtf(var + BN_EPS);
            ssf[tid]      = s;
            ssf[64 + tid] = beta[tid] - s * mu;
        }
        __syncthreads();
    }

    // stage W^T bf16
    for (int idx = tid; idx < 64 * 64; idx += 256) {
        int k = idx >> 6, n = idx & 63;
        wt_lds[n * WS + k] = (short)bf16_1(W[idx]);
    }

    // gather A-tile: 8 lanes/row, uint4 per lane, 2 passes of 32 rows
    const uint4* hb4 = (const uint4*)hb;
    const int cc = tid & 7;
    const int rl = tid >> 3;
    float sc[8], sh[8];
    if (BN) {
        #pragma unroll
        for (int j = 0; j < 8; j++) {
            sc[j] = ssf[cc * 8 + j];
            sh[j] = ssf[64 + cc * 8 + j];
        }
    }
    #pragma unroll
    for (int it = 0; it < 2; it++) {
        int rloc = it * 32 + rl;
        int n = nb + rloc;
        float acc[8] = {0.f, 0.f, 0.f, 0.f, 0.f, 0.f, 0.f, 0.f};
        if (n < N) {
            uint4 p = hb4[(size_t)n * 8 + cc];
            acc_row8<BN>(acc, p, sc, sh);
            int e = rowp[n], end = rowp[n + 1];
            for (; e + 3 < end; e += 4) {
                int a0 = srcs[e], a1 = srcs[e + 1], a2 = srcs[e + 2], a3 = srcs[e + 3];
                uint4 p0 = hb4[(size_t)a0 * 8 + cc];
                uint4 p1 = hb4[(size_t)a1 * 8 + cc];
                uint4 p2 = hb4[(size_t)a2 * 8 + cc];
                uint4 p3 = hb4[(size_t)a3 * 8 + cc];
                acc_row8<BN>(acc, p0, sc, sh);
                acc_row8<BN>(acc, p1, sc, sh);
                acc_row8<BN>(acc, p2, sc, sh);
                acc_row8<BN>(acc, p3, sc, sh);
            }
            for (; e < end; e++) {
                uint4 pp = hb4[(size_t)srcs[e] * 8 + cc];
                acc_row8<BN>(acc, pp, sc, sh);
            }
        }
        uint4 o;
        o.x = pack_bf16x2(acc[0], acc[1]);
        o.y = pack_bf16x2(acc[2], acc[3]);
        o.z = pack_bf16x2(acc[4], acc[5]);
        o.w = pack_bf16x2(acc[6], acc[7]);
        *(uint4*)&a_lds[rloc * AS + cc * 8] = o;
    }
    __syncthreads();

    // fragments: wave w -> rows [w*16, w*16+16)
    short8 afrag[KH], bfrag[4][KH];
    const int rw = w * 16;
    #pragma unroll
    for (int kh = 0; kh < KH; kh++)
        afrag[kh] = *(const short8*)&a_lds[(rw + ln) * AS + kh * 32 + q * 8];
    #pragma unroll
    for (int nt = 0; nt < 4; nt++)
        #pragma unroll
        for (int kh = 0; kh < KH; kh++)
            bfrag[nt][kh] = *(const short8*)&wt_lds[(nt * 16 + ln) * WS + kh * 32 + q * 8];

    f32x4 acc[4];
    #pragma unroll
    for (int nt = 0; nt < 4; nt++) {
        float bv = bias[nt * 16 + ln];
        acc[nt] = (f32x4){bv, bv, bv, bv};
    }
    #pragma unroll
    for (int kh = 0; kh < KH; kh++)
        #pragma unroll
        for (int nt = 0; nt < 4; nt++)
            acc[nt] = __builtin_amdgcn_mfma_f32_16x16x32_bf16(
                afrag[kh], bfrag[nt][kh], acc[nt], 0, 0, 0);

    #pragma unroll
    for (int reg = 0; reg < 4; reg++) {
        int row = nb + rw + q * 4 + reg;
        if (row < N)
            #pragma unroll
            for (int nt = 0; nt < 4; nt++)
                out[(size_t)row * 64 + nt * 16 + ln] = bf16_1(acc[nt][reg]);
    }

    // column stats of output
    {
        float s1[4] = {0.f, 0.f, 0.f, 0.f};
        float s2[4] = {0.f, 0.f, 0.f, 0.f};
        #pragma unroll
        for (int reg = 0; reg < 4; reg++) {
            int row = nb + rw + q * 4 + reg;
            if (row < N)
                #pragma unroll
                for (int nt = 0; nt < 4; nt++) {
                    float v = acc[nt][reg];
                    s1[nt] += v;
                    s2[nt] += v * v;
                }
        }
        #pragma unroll
        for (int nt = 0; nt < 4; nt++) {
            s1[nt] += __shfl_xor(s1[nt], 16);
            s1[nt] += __shfl_xor(s1[nt], 32);
            s2[nt] += __shfl_xor(s2[nt], 16);
            s2[nt] += __shfl_xor(s2[nt], 32);
        }
        __syncthreads();
        if (l < 16) {
            #pragma unroll
            for (int nt = 0; nt < 4; nt++) {
                red[w * 64 + nt * 16 + l]       = s1[nt];
                red[256 + w * 64 + nt * 16 + l] = s2[nt];
            }
        }
        __syncthreads();
        if (tid < 64) {
            float t1 = red[tid] + red[64 + tid] + red[128 + tid] + red[192 + tid];
            float t2 = red[256 + tid] + red[320 + tid] + red[384 + tid] + red[448 + tid];
            unsafeAtomicAdd(&stat_sum[tid],   t1);
            unsafeAtomicAdd(&stat_sumsq[tid], t2);
        }
    }
}

// ---------------------------------------------------------------------------
// Plain MFMA GEMM (encoder INK=1 fp32 input; GEMM2 INK=2 BN+ReLU from stats)
template<int K, int INK, bool STATS>
__global__ __launch_bounds__(256)
void mfma_gemm(const void* __restrict__ Av,
               const float* __restrict__ bn_sum, const float* __restrict__ bn_sumsq,
               const float* __restrict__ gamma, const float* __restrict__ beta,
               float invN,
               const float* __restrict__ W, const float* __restrict__ bias,
               unsigned short* __restrict__ out,
               float* __restrict__ stat_sum, float* __restrict__ stat_sumsq,
               int N)
{
    constexpr int AS  = K + 8;
    constexpr int WS  = K + 8;
    constexpr int CPR = K / 8;
    constexpr int KH  = K / 32;

    __shared__ short a_lds[128 * AS];
    __shared__ short wt_lds[64 * WS];
    __shared__ float ssf[128];
    __shared__ float red[512];

    const int tid = threadIdx.x;
    const int nb  = blockIdx.x * 128;
    const int l   = tid & 63;
    const int w   = tid >> 6;
    const int ln  = l & 15;
    const int q   = l >> 4;

    if (INK == 2) {
        if (tid < 64) {
            float mu  = bn_sum[tid] * invN;
            float var = bn_sumsq[tid] * invN - mu * mu;
            float s   = gamma[tid] * rsqrtf(var + BN_EPS);
            ssf[tid]      = s;
            ssf[64 + tid] = beta[tid] - s * mu;
        }
        __syncthreads();
    }

    for (int idx = tid; idx < K * 64; idx += 256) {
        int k = idx >> 6, n = idx & 63;
        wt_lds[n * WS + k] = (short)bf16_1(W[idx]);
    }

    for (int c = tid; c < 128 * CPR; c += 256) {
        int rloc = c / CPR;
        int j    = c % CPR;
        int row  = nb + rloc;
        uint4 p = make_uint4(0u, 0u, 0u, 0u);
        if (row < N) {
            if (INK == 1) {
                const float4* xr = (const float4*)Av;
                float4 f0 = xr[(size_t)row * (K / 4) + 2 * j];
                float4 f1 = xr[(size_t)row * (K / 4) + 2 * j + 1];
                p.x = pack_bf16x2(f0.x, f0.y); p.y = pack_bf16x2(f0.z, f0.w);
                p.z = pack_bf16x2(f1.x, f1.y); p.w = pack_bf16x2(f1.z, f1.w);
            } else {
                p = ((const uint4*)Av)[(size_t)row * CPR + j];
                if (INK == 2) {
                    int k0 = j * 8;
                    unsigned int* pp = (unsigned int*)&p;
                    #pragma unroll
                    for (int t = 0; t < 4; t++) {
                        float2 f = unpack_bf16x2(pp[t]);
                        int k = k0 + 2 * t;
                        f.x = fmaxf(fmaf(f.x, ssf[k],     ssf[64 + k]),     0.f);
                        f.y = fmaxf(fmaf(f.y, ssf[k + 1], ssf[64 + k + 1]), 0.f);
                        pp[t] = pack_bf16x2(f.x, f.y);
                    }
                }
            }
        }
        *(uint4*)&a_lds[rloc * AS + j * 8] = p;
    }
    __syncthreads();

    short8 afrag[2][KH], bfrag[4][KH];
    const int rw = w * 32;
    #pragma unroll
    for (int mt = 0; mt < 2; mt++)
        #pragma unroll
        for (int kh = 0; kh < KH; kh++)
            afrag[mt][kh] = *(const short8*)&a_lds[(rw + mt * 16 + ln) * AS + kh * 32 + q * 8];
    #pragma unroll
    for (int nt = 0; nt < 4; nt++)
        #pragma unroll
        for (int kh = 0; kh < KH; kh++)
            bfrag[nt][kh] = *(const short8*)&wt_lds[(nt * 16 + ln) * WS + kh * 32 + q * 8];

    f32x4 acc[2][4];
    #pragma unroll
    for (int nt = 0; nt < 4; nt++) {
        float bv = bias[nt * 16 + ln];
        #pragma unroll
        for (int mt = 0; mt < 2; mt++)
            acc[mt][nt] = (f32x4){bv, bv, bv, bv};
    }
    #pragma unroll
    for (int kh = 0; kh < KH; kh++)
        #pragma unroll
        for (int mt = 0; mt < 2; mt++)
            #pragma unroll
            for (int nt = 0; nt < 4; nt++)
                acc[mt][nt] = __builtin_amdgcn_mfma_f32_16x16x32_bf16(
                    afrag[mt][kh], bfrag[nt][kh], acc[mt][nt], 0, 0, 0);

    #pragma unroll
    for (int mt = 0; mt < 2; mt++)
        #pragma unroll
        for (int reg = 0; reg < 4; reg++) {
            int row = nb + rw + mt * 16 + q * 4 + reg;
            if (row < N)
                #pragma unroll
                for (int nt = 0; nt < 4; nt++)
                    out[(size_t)row * 64 + nt * 16 + ln] = bf16_1(acc[mt][nt][reg]);
        }

    if (STATS) {
        float s1[4] = {0.f, 0.f, 0.f, 0.f};
        float s2[4] = {0.f, 0.f, 0.f, 0.f};
        #pragma unroll
        for (int mt = 0; mt < 2; mt++)
            #pragma unroll
            for (int reg = 0; reg < 4; reg++) {
                int row = nb + rw + mt * 16 + q * 4 + reg;
                if (row < N)
                    #pragma unroll
                    for (int nt = 0; nt < 4; nt++) {
                        float v = acc[mt][nt][reg];
                        s1[nt] += v;
                        s2[nt] += v * v;
                    }
            }
        #pragma unroll
        for (int nt = 0; nt < 4; nt++) {
            s1[nt] += __shfl_xor(s1[nt], 16);
            s1[nt] += __shfl_xor(s1[nt], 32);
            s2[nt] += __shfl_xor(s2[nt], 16);
            s2[nt] += __shfl_xor(s2[nt], 32);
        }
        __syncthreads();
        if (l < 16) {
            #pragma unroll
            for (int nt = 0; nt < 4; nt++) {
                red[w * 64 + nt * 16 + l]       = s1[nt];
                red[256 + w * 64 + nt * 16 + l] = s2[nt];
            }
        }
        __syncthreads();
        if (tid < 64) {
            float t1 = red[tid] + red[64 + tid] + red[128 + tid] + red[192 + tid];
            float t2 = red[256 + tid] + red[320 + tid] + red[384 + tid] + red[448 + tid];
            unsafeAtomicAdd(&stat_sum[tid],   t1);
            unsafeAtomicAdd(&stat_sumsq[tid], t2);
        }
    }
}

// ---------------------------------------------------------------------------
// Bucketed CSR build (bucket = dst>>7, <=800 buckets)
__global__ __launch_bounds__(256)
void bucket_hist(const int* __restrict__ dst, int* __restrict__ bhist,
                 int E, int nb)
{
    __shared__ int lh[1024];
    for (int i = threadIdx.x; i < 1024; i += 256) lh[i] = 0;
    __syncthreads();
    for (int e = blockIdx.x * 256 + threadIdx.x; e < E; e += gridDim.x * 256)
        atomicAdd(&lh[dst[e] >> 7], 1);
    __syncthreads();
    for (int i = threadIdx.x; i < nb; i += 256)
        if (lh[i]) atomicAdd(&bhist[i], lh[i]);
}

__global__ __launch_bounds__(1024)
void bucket_scan(const int* __restrict__ bhist, int* __restrict__ bbase,
                 int* __restrict__ bcur, int nb)
{
    __shared__ int sm[1024];
    int t = threadIdx.x;
    int v = (t < nb) ? bhist[t] : 0;
    sm[t] = v; __syncthreads();
    for (int off = 1; off < 1024; off <<= 1) {
        int add = (t >= off) ? sm[t - off] : 0;
        __syncthreads();
        sm[t] += add;
        __syncthreads();
    }
    if (t <= nb) {
        int ex = sm[t] - v;
        bbase[t] = ex;
        if (t < nb) bcur[t * CURS_STRIDE] = ex;
    }
}

__global__ __launch_bounds__(256)
void bucket_scatter(const int* __restrict__ src, const int* __restrict__ dst,
                    int* __restrict__ bcur, int* __restrict__ ebuf,
                    int E, int nb)
{
    constexpr int CH = 4096;
    __shared__ int            key[CH];
    __shared__ unsigned short bid[CH];
    __shared__ int lh[800];
    __shared__ int lbase[800];

    const int t    = threadIdx.x;
    const int base = blockIdx.x * CH;
    const int cnt  = min(CH, E - base);

    for (int i = t; i < nb; i += 256) lh[i] = 0;
    __syncthreads();

    for (int i = t; i < cnt; i += 256) {
        int d = dst[base + i];
        int s = src[base + i];
        int b = d >> 7;
        key[i] = (s << 7) | (d & 127);
        bid[i] = (unsigned short)b;
        atomicAdd(&lh[b], 1);
    }
    __syncthreads();

    for (int i = t; i < nb; i += 256) {
        int c = lh[i];
        if (c) lbase[i] = atomicAdd(&bcur[i * CURS_STRIDE], c);
        lh[i] = 0;
    }
    __syncthreads();

    for (int i = t; i < cnt; i += 256) {
        int b = bid[i];
        int p = atomicAdd(&lh[b], 1);
        ebuf[lbase[b] + p] = key[i];
    }
}

__global__ __launch_bounds__(256)
void bucket_csr(const int* __restrict__ bbase, const int* __restrict__ ebuf,
                int* __restrict__ row, int* __restrict__ srcs, int N, int E)
{
    __shared__ int lh[128], lofs[128], lcur[128];
    const int b   = blockIdx.x;
    const int tid = threadIdx.x;
    const int beg = bbase[b], end = bbase[b + 1];

    if (tid < 128) lh[tid] = 0;
    __syncthreads();
    for (int e = beg + tid; e < end; e += 256)
        atomicAdd(&lh[ebuf[e] & 127], 1);
    __syncthreads();

    int v = (tid < 128) ? lh[tid] : 0;
    if (tid < 128) lofs[tid] = v;
    __syncthreads();
    for (int off = 1; off < 128; off <<= 1) {
        int add = 0;
        if (tid < 128 && tid >= off) add = lofs[tid - off];
        __syncthreads();
        if (tid < 128) lofs[tid] += add;
        __syncthreads();
    }
    if (tid < 128) {
        int ex = lofs[tid] - v;
        lcur[tid] = ex;
        int node = b * 128 + tid;
        if (node < N) row[node] = beg + ex;
    }
    if (b == 0 && tid == 0) row[N] = E;
    __syncthreads();

    for (int e = beg + tid; e < end; e += 256) {
        int pk = ebuf[e];
        int p = atomicAdd(&lcur[pk & 127], 1);
        srcs[beg + p] = pk >> 7;
    }
}

// ---------------------------------------------------------------------------
__global__ __launch_bounds__(256)
void pool_nodes(const unsigned short* __restrict__ hb,
                const float* __restrict__ bsum, const float* __restrict__ bsumsq,
                const float* __restrict__ gamma, const float* __restrict__ beta,
                float invN, const int* __restrict__ batch,
                float* __restrict__ pooled, int N)
{
    int d  = threadIdx.x & 63;
    int nl = threadIdx.x >> 6;
    int nb = blockIdx.x * 32;
    float mu  = bsum[d] * invN;
    float var = bsumsq[d] * invN - mu * mu;
    float s   = gamma[d] * rsqrtf(var + BN_EPS);
    float sh  = beta[d] - s * mu;
    float acc = 0.f;
    int cg = -1;
    #pragma unroll
    for (int r = 0; r < 8; r++) {
        int n = nb + nl * 8 + r;
        if (n >= N) break;
        int g = batch[n];
        if (g != cg) {
            if (cg >= 0) unsafeAtomicAdd(&pooled[(size_t)cg * 64 + d], acc);
            acc = 0.f; cg = g;
        }
        float v = __uint_as_float(((unsigned int)hb[(size_t)n * 64 + d]) << 16);
        acc += fmaxf(fmaf(v, s, sh), 0.f);
    }
    if (cg >= 0) unsafeAtomicAdd(&pooled[(size_t)cg * 64 + d], acc);
}

__global__ __launch_bounds__(256)
void pool_x(const float* __restrict__ x, const int* __restrict__ batch,
            float* __restrict__ px, int N)
{
    int f  = threadIdx.x & 31;
    int nl = threadIdx.x >> 5;
    int nb = blockIdx.x * 64;
    float acc = 0.f;
    int cg = -1;
    #pragma unroll
    for (int r = 0; r < 8; r++) {
        int n = nb + nl * 8 + r;
        if (n >= N) break;
        int g = batch[n];
        if (g != cg) {
            if (cg >= 0) unsafeAtomicAdd(&px[(size_t)cg * 32 + f], acc);
            acc = 0.f; cg = g;
        }
        acc += x[(size_t)n * 32 + f];
    }
    if (cg >= 0) unsafeAtomicAdd(&px[(size_t)cg * 32 + f], acc);
}

// ---------------------------------------------------------------------------
__global__ __launch_bounds__(256)
void head_kernel(const float* __restrict__ px, const float* __restrict__ pl,
                 const float* __restrict__ fcW0, const float* __restrict__ fcb0,
                 const float* __restrict__ fcW, const float* __restrict__ fcb,
                 const int* __restrict__ y, float* __restrict__ out, int G)
{
    int tid = blockIdx.x * 256 + threadIdx.x;
    int total = G * 10;
    if (tid < total) {
        int g = tid / 10, c = tid % 10;
        float acc = fcb0[c];
        const float* pxg = px + (size_t)g * 32;
        #pragma unroll
        for (int k = 0; k < 32; k++) acc = fmaf(pxg[k], fcW0[k * 10 + c], acc);
        #pragma unroll
        for (int i = 0; i < 4; i++) {
            acc += fcb[i * 10 + c];
            const float* pg = pl + ((size_t)i * G + g) * 64;
            const float* w  = fcW + i * 640;
            #pragma unroll
            for (int k = 0; k < 64; k++) acc = fmaf(pg[k], w[k * 10 + c], acc);
        }
        out[tid] = acc;
    } else if (tid < total + G) {
        out[tid] = (float)y[tid - total];
    }
}

// ---------------------------------------------------------------------------
extern "C" void kernel_launch(void* const* d_in, const int* in_sizes, int n_in,
                              void* d_out, int out_size, void* d_ws, size_t ws_size,
                              hipStream_t stream)
{
    const float* x     = (const float*)d_in[0];
    const int*   ei    = (const int*)  d_in[1];
    const int*   batch = (const int*)  d_in[2];
    const int*   y     = (const int*)  d_in[3];
    const float* W_enc = (const float*)d_in[4];
    const float* b_enc = (const float*)d_in[5];
    const float* W1    = (const float*)d_in[6];
    const float* b1    = (const float*)d_in[7];
    const float* g1    = (const float*)d_in[8];
    const float* be1   = (const float*)d_in[9];
    const float* W2    = (const float*)d_in[10];
    const float* b2    = (const float*)d_in[11];
    const float* gout  = (const float*)d_in[12];
    const float* bout  = (const float*)d_in[13];
    const float* fcW0  = (const float*)d_in[14];
    const float* fcb0  = (const float*)d_in[15];
    const float* fcW   = (const float*)d_in[16];
    const float* fcb   = (const float*)d_in[17];

    const int N = in_sizes[0] / 32;   // 100000
    const int E = in_sizes[1] / 2;    // 1600000
    const int G = in_sizes[3];        // 2000
    const int* src = ei;
    const int* dst = ei + E;
    const int NB = (N + 127) / 128;   // 782 buckets

    // ws layout: m bf16 | hb bf16 | stats | px | pl | row | srcs
    unsigned int* m  = (unsigned int*)d_ws;          // N*32 uints
    unsigned int* hb = m + (size_t)N * 32;           // N*32 uints
    float* stats = (float*)(hb + (size_t)N * 32);    // [4][2] x 128
    float* px    = stats + 1024;                     // G*32
    float* pl    = px + (size_t)G * 32;              // 4*G*64
    int*   row   = (int*)(pl + (size_t)4 * G * 64);  // N+1
    int*   srcs  = row + (N + 1);                    // E
    // CSR temps alias m (dead before layer-0 gin_gemm1 writes m)
    int*   mi    = (int*)m;
    int*   bhist = mi;
    int*   bbase = mi + 1024;
    int*   bcur  = mi + 2048;
    int*   ebuf  = mi + 2048 + 800 * CURS_STRIDE;

    size_t zbytes = (size_t)(1024 + G * 32 + 4 * G * 64) * sizeof(float);
    hipMemsetAsync(stats, 0, zbytes, stream);
    hipMemsetAsync(bhist, 0, 1024 * sizeof(int), stream);

    // bucketed CSR build
    bucket_hist<<<160, 256, 0, stream>>>(dst, bhist, E, NB);
    bucket_scan<<<1, 1024, 0, stream>>>(bhist, bbase, bcur, NB);
    bucket_scatter<<<(E + 4095) / 4096, 256, 0, stream>>>(src, dst, bcur, ebuf, E, NB);
    bucket_csr<<<NB, 256, 0, stream>>>(bbase, ebuf, row, srcs, N, E);

    const int gb   = NB;               // 128-row tiles (encoder, GEMM2)
    const int gb64 = (N + 63) / 64;    // 64-row tiles (gin_gemm1)
    const float invN = 1.0f / (float)N;

    // encoder: hb = bf16(x @ W_enc + b_enc)
    mfma_gemm<32, 1, false><<<gb, 256, 0, stream>>>(
        x, nullptr, nullptr, nullptr, nullptr, 0.f,
        W_enc, b_enc, (unsigned short*)hb, nullptr, nullptr, N);
    pool_x<<<(N + 63) / 64, 256, 0, stream>>>(x, batch, px, N);

    for (int i = 0; i < 4; i++) {
        float* s1a = stats + (i * 2 + 0) * 128;
        float* s1b = s1a + 64;
        float* s2a = stats + (i * 2 + 1) * 128;
        float* s2b = s2a + 64;

        // m = bf16( (t(hb[n]) + sum t(hb[nbr])) @ W1 + b1 ) + stats s1 (fused)
        if (i == 0) {
            gin_gemm1<false><<<gb64, 256, 0, stream>>>(
                row, srcs, hb, nullptr, nullptr, nullptr, nullptr, 0.f,
                W1 + (size_t)i * 4096, b1 + i * 64, (unsigned short*)m, s1a, s1b, N);
        } else {
            float* p2a = stats + ((i - 1) * 2 + 1) * 128;
            float* p2b = p2a + 64;
            gin_gemm1<true><<<gb64, 256, 0, stream>>>(
                row, srcs, hb, p2a, p2b,
                gout + (i - 1) * 64, bout + (i - 1) * 64, invN,
                W1 + (size_t)i * 4096, b1 + i * 64, (unsigned short*)m, s1a, s1b, N);
        }

        // hb = bf16( relu(bn1(m)) @ W2[i] + b2[i] ) + stats s2
        mfma_gemm<64, 2, true><<<gb, 256, 0, stream>>>(
            m, s1a, s1b, g1 + i * 64, be1 + i * 64, invN,
            W2 + (size_t)i * 4096, b2 + i * 64, (unsigned short*)hb, s2a, s2b, N);

        // pl[i][g] += relu(bn2(hb))
        pool_nodes<<<(N + 31) / 32, 256, 0, stream>>>(
            (const unsigned short*)hb, s2a, s2b, gout + i * 64, bout + i * 64, invN,
            batch, pl + (size_t)i * G * 64, N);
    }

    head_kernel<<<(G * 10 + G + 255) / 256, 256, 0, stream>>>(
        px, pl, fcW0, fcb0, fcW, fcb, y, (float*)d_out, G);
}

// Round 12
// 580.780 us; speedup vs baseline: 5.2156x; 1.0624x over previous
//
#include <hip/hip_runtime.h>

// GIN round 12: un-fused conv stage-1. Standalone max-occupancy gather
// (agg_bn: no LDS, 3125 blocks, BN folded, bf16 in/out) + plain MFMA GEMM1
// in-place. Rationale: r5 showed the standalone gather sustains ~2x the
// scattered-line throughput of the r8 fused kernel (LDS/grid-throttled).
// Everything else identical to round 8 (best = 565 us).

#define BN_EPS 1e-5f
#define CURS_STRIDE 16

typedef __attribute__((ext_vector_type(8))) short short8;
typedef __attribute__((ext_vector_type(4))) float f32x4;

// ---- bf16 helpers (rne) ----
__device__ __forceinline__ unsigned int pack_bf16x2(float a, float b) {
    unsigned int ua = __float_as_uint(a);
    unsigned int ub = __float_as_uint(b);
    ua = (ua + 0x7FFFu + ((ua >> 16) & 1u)) >> 16;
    ub = (ub + 0x7FFFu + ((ub >> 16) & 1u)) >> 16;
    return ua | (ub << 16);
}
__device__ __forceinline__ unsigned short bf16_1(float f) {
    unsigned int u = __float_as_uint(f);
    u = (u + 0x7FFFu + ((u >> 16) & 1u)) >> 16;
    return (unsigned short)u;
}
__device__ __forceinline__ float2 unpack_bf16x2(unsigned int u) {
    float2 r;
    r.x = __uint_as_float(u << 16);
    r.y = __uint_as_float(u & 0xFFFF0000u);
    return r;
}

template<bool BN>
__device__ __forceinline__ void acc_row8(float (&acc)[8], uint4 p,
                                         const float* sc, const float* sh) {
    unsigned int pp[4] = {p.x, p.y, p.z, p.w};
    #pragma unroll
    for (int t = 0; t < 4; t++) {
        float2 f = unpack_bf16x2(pp[t]);
        if (BN) {
            f.x = fmaxf(fmaf(f.x, sc[2 * t],     sh[2 * t]),     0.f);
            f.y = fmaxf(fmaf(f.y, sc[2 * t + 1], sh[2 * t + 1]), 0.f);
        }
        acc[2 * t]     += f.x;
        acc[2 * t + 1] += f.y;
    }
}

// ---------------------------------------------------------------------------
// Standalone gather: a[n] = t(hb[n]) + sum_{s in nbrs(n)} t(hb[s]); bf16 out.
// 8 lanes/row, uint4/lane, no LDS -> max occupancy. t = BN?relu(v*s+sh):v.
template<bool BN>
__global__ __launch_bounds__(256)
void agg_bn(const int* __restrict__ rowp, const int* __restrict__ srcs,
            const unsigned int* __restrict__ hb,
            const float* __restrict__ bsum, const float* __restrict__ bsumsq,
            const float* __restrict__ gamma, const float* __restrict__ beta,
            float invN, unsigned int* __restrict__ a_out, int N)
{
    int tid = blockIdx.x * 256 + threadIdx.x;
    int n  = tid >> 3;
    if (n >= N) return;
    int cc = tid & 7;

    float sc[8], sh[8];
    if (BN) {
        #pragma unroll
        for (int j = 0; j < 8; j++) {
            int d = cc * 8 + j;
            float mu  = bsum[d] * invN;
            float var = bsumsq[d] * invN - mu * mu;
            float s   = gamma[d] * rsqrtf(var + BN_EPS);
            sc[j] = s;
            sh[j] = beta[d] - s * mu;
        }
    }

    const uint4* hb4 = (const uint4*)hb;
    float acc[8] = {0.f, 0.f, 0.f, 0.f, 0.f, 0.f, 0.f, 0.f};
    acc_row8<BN>(acc, hb4[(size_t)n * 8 + cc], sc, sh);

    int e = rowp[n], end = rowp[n + 1];
    for (; e + 3 < end; e += 4) {
        int a0 = srcs[e], a1 = srcs[e + 1], a2 = srcs[e + 2], a3 = srcs[e + 3];
        uint4 p0 = hb4[(size_t)a0 * 8 + cc];
        uint4 p1 = hb4[(size_t)a1 * 8 + cc];
        uint4 p2 = hb4[(size_t)a2 * 8 + cc];
        uint4 p3 = hb4[(size_t)a3 * 8 + cc];
        acc_row8<BN>(acc, p0, sc, sh);
        acc_row8<BN>(acc, p1, sc, sh);
        acc_row8<BN>(acc, p2, sc, sh);
        acc_row8<BN>(acc, p3, sc, sh);
    }
    for (; e < end; e++)
        acc_row8<BN>(acc, hb4[(size_t)srcs[e] * 8 + cc], sc, sh);

    uint4 o;
    o.x = pack_bf16x2(acc[0], acc[1]);
    o.y = pack_bf16x2(acc[2], acc[3]);
    o.z = pack_bf16x2(acc[4], acc[5]);
    o.w = pack_bf16x2(acc[6], acc[7]);
    ((uint4*)a_out)[(size_t)n * 8 + cc] = o;
}

// ---------------------------------------------------------------------------
// Plain MFMA GEMM. INK 0: A packed bf16 passthrough; INK 1: A fp32 (encoder);
// INK 2: A packed bf16 with BN+ReLU from raw stats. In-place safe.
template<int K, int INK, bool STATS>
__global__ __launch_bounds__(256)
void mfma_gemm(const void* __restrict__ Av,
               const float* __restrict__ bn_sum, const float* __restrict__ bn_sumsq,
               const float* __restrict__ gamma, const float* __restrict__ beta,
               float invN,
               const float* __restrict__ W, const float* __restrict__ bias,
               unsigned short* __restrict__ out,
               float* __restrict__ stat_sum, float* __restrict__ stat_sumsq,
               int N)
{
    constexpr int AS  = K + 8;
    constexpr int WS  = K + 8;
    constexpr int CPR = K / 8;
    constexpr int KH  = K / 32;

    __shared__ short a_lds[128 * AS];
    __shared__ short wt_lds[64 * WS];
    __shared__ float ssf[128];
    __shared__ float red[512];

    const int tid = threadIdx.x;
    const int nb  = blockIdx.x * 128;
    const int l   = tid & 63;
    const int w   = tid >> 6;
    const int ln  = l & 15;
    const int q   = l >> 4;

    if (INK == 2) {
        if (tid < 64) {
            float mu  = bn_sum[tid] * invN;
            float var = bn_sumsq[tid] * invN - mu * mu;
            float s   = gamma[tid] * rsqrtf(var + BN_EPS);
            ssf[tid]      = s;
            ssf[64 + tid] = beta[tid] - s * mu;
        }
        __syncthreads();
    }

    for (int idx = tid; idx < K * 64; idx += 256) {
        int k = idx >> 6, n = idx & 63;
        wt_lds[n * WS + k] = (short)bf16_1(W[idx]);
    }

    for (int c = tid; c < 128 * CPR; c += 256) {
        int rloc = c / CPR;
        int j    = c % CPR;
        int row  = nb + rloc;
        uint4 p = make_uint4(0u, 0u, 0u, 0u);
        if (row < N) {
            if (INK == 1) {
                const float4* xr = (const float4*)Av;
                float4 f0 = xr[(size_t)row * (K / 4) + 2 * j];
                float4 f1 = xr[(size_t)row * (K / 4) + 2 * j + 1];
                p.x = pack_bf16x2(f0.x, f0.y); p.y = pack_bf16x2(f0.z, f0.w);
                p.z = pack_bf16x2(f1.x, f1.y); p.w = pack_bf16x2(f1.z, f1.w);
            } else {
                p = ((const uint4*)Av)[(size_t)row * CPR + j];
                if (INK == 2) {
                    int k0 = j * 8;
                    unsigned int* pp = (unsigned int*)&p;
                    #pragma unroll
                    for (int t = 0; t < 4; t++) {
                        float2 f = unpack_bf16x2(pp[t]);
                        int k = k0 + 2 * t;
                        f.x = fmaxf(fmaf(f.x, ssf[k],     ssf[64 + k]),     0.f);
                        f.y = fmaxf(fmaf(f.y, ssf[k + 1], ssf[64 + k + 1]), 0.f);
                        pp[t] = pack_bf16x2(f.x, f.y);
                    }
                }
            }
        }
        *(uint4*)&a_lds[rloc * AS + j * 8] = p;
    }
    __syncthreads();

    short8 afrag[2][KH], bfrag[4][KH];
    const int rw = w * 32;
    #pragma unroll
    for (int mt = 0; mt < 2; mt++)
        #pragma unroll
        for (int kh = 0; kh < KH; kh++)
            afrag[mt][kh] = *(const short8*)&a_lds[(rw + mt * 16 + ln) * AS + kh * 32 + q * 8];
    #pragma unroll
    for (int nt = 0; nt < 4; nt++)
        #pragma unroll
        for (int kh = 0; kh < KH; kh++)
            bfrag[nt][kh] = *(const short8*)&wt_lds[(nt * 16 + ln) * WS + kh * 32 + q * 8];

    f32x4 acc[2][4];
    #pragma unroll
    for (int nt = 0; nt < 4; nt++) {
        float bv = bias[nt * 16 + ln];
        #pragma unroll
        for (int mt = 0; mt < 2; mt++)
            acc[mt][nt] = (f32x4){bv, bv, bv, bv};
    }
    #pragma unroll
    for (int kh = 0; kh < KH; kh++)
        #pragma unroll
        for (int mt = 0; mt < 2; mt++)
            #pragma unroll
            for (int nt = 0; nt < 4; nt++)
                acc[mt][nt] = __builtin_amdgcn_mfma_f32_16x16x32_bf16(
                    afrag[mt][kh], bfrag[nt][kh], acc[mt][nt], 0, 0, 0);

    #pragma unroll
    for (int mt = 0; mt < 2; mt++)
        #pragma unroll
        for (int reg = 0; reg < 4; reg++) {
            int row = nb + rw + mt * 16 + q * 4 + reg;
            if (row < N)
                #pragma unroll
                for (int nt = 0; nt < 4; nt++)
                    out[(size_t)row * 64 + nt * 16 + ln] = bf16_1(acc[mt][nt][reg]);
        }

    if (STATS) {
        float s1[4] = {0.f, 0.f, 0.f, 0.f};
        float s2[4] = {0.f, 0.f, 0.f, 0.f};
        #pragma unroll
        for (int mt = 0; mt < 2; mt++)
            #pragma unroll
            for (int reg = 0; reg < 4; reg++) {
                int row = nb + rw + mt * 16 + q * 4 + reg;
                if (row < N)
                    #pragma unroll
                    for (int nt = 0; nt < 4; nt++) {
                        float v = acc[mt][nt][reg];
                        s1[nt] += v;
                        s2[nt] += v * v;
                    }
            }
        #pragma unroll
        for (int nt = 0; nt < 4; nt++) {
            s1[nt] += __shfl_xor(s1[nt], 16);
            s1[nt] += __shfl_xor(s1[nt], 32);
            s2[nt] += __shfl_xor(s2[nt], 16);
            s2[nt] += __shfl_xor(s2[nt], 32);
        }
        __syncthreads();
        if (l < 16) {
            #pragma unroll
            for (int nt = 0; nt < 4; nt++) {
                red[w * 64 + nt * 16 + l]       = s1[nt];
                red[256 + w * 64 + nt * 16 + l] = s2[nt];
            }
        }
        __syncthreads();
        if (tid < 64) {
            float t1 = red[tid] + red[64 + tid] + red[128 + tid] + red[192 + tid];
            float t2 = red[256 + tid] + red[320 + tid] + red[384 + tid] + red[448 + tid];
            unsafeAtomicAdd(&stat_sum[tid],   t1);
            unsafeAtomicAdd(&stat_sumsq[tid], t2);
        }
    }
}

// ---------------------------------------------------------------------------
// Bucketed CSR build (bucket = dst>>7, <=800 buckets)
__global__ __launch_bounds__(256)
void bucket_hist(const int* __restrict__ dst, int* __restrict__ bhist,
                 int E, int nb)
{
    __shared__ int lh[1024];
    for (int i = threadIdx.x; i < 1024; i += 256) lh[i] = 0;
    __syncthreads();
    for (int e = blockIdx.x * 256 + threadIdx.x; e < E; e += gridDim.x * 256)
        atomicAdd(&lh[dst[e] >> 7], 1);
    __syncthreads();
    for (int i = threadIdx.x; i < nb; i += 256)
        if (lh[i]) atomicAdd(&bhist[i], lh[i]);
}

__global__ __launch_bounds__(1024)
void bucket_scan(const int* __restrict__ bhist, int* __restrict__ bbase,
                 int* __restrict__ bcur, int nb)
{
    __shared__ int sm[1024];
    int t = threadIdx.x;
    int v = (t < nb) ? bhist[t] : 0;
    sm[t] = v; __syncthreads();
    for (int off = 1; off < 1024; off <<= 1) {
        int add = (t >= off) ? sm[t - off] : 0;
        __syncthreads();
        sm[t] += add;
        __syncthreads();
    }
    if (t <= nb) {
        int ex = sm[t] - v;
        bbase[t] = ex;
        if (t < nb) bcur[t * CURS_STRIDE] = ex;
    }
}

__global__ __launch_bounds__(256)
void bucket_scatter(const int* __restrict__ src, const int* __restrict__ dst,
                    int* __restrict__ bcur, int* __restrict__ ebuf,
                    int E, int nb)
{
    constexpr int CH = 4096;
    __shared__ int            key[CH];
    __shared__ unsigned short bid[CH];
    __shared__ int lh[800];
    __shared__ int lbase[800];

    const int t    = threadIdx.x;
    const int base = blockIdx.x * CH;
    const int cnt  = min(CH, E - base);

    for (int i = t; i < nb; i += 256) lh[i] = 0;
    __syncthreads();

    for (int i = t; i < cnt; i += 256) {
        int d = dst[base + i];
        int s = src[base + i];
        int b = d >> 7;
        key[i] = (s << 7) | (d & 127);
        bid[i] = (unsigned short)b;
        atomicAdd(&lh[b], 1);
    }
    __syncthreads();

    for (int i = t; i < nb; i += 256) {
        int c = lh[i];
        if (c) lbase[i] = atomicAdd(&bcur[i * CURS_STRIDE], c);
        lh[i] = 0;
    }
    __syncthreads();

    for (int i = t; i < cnt; i += 256) {
        int b = bid[i];
        int p = atomicAdd(&lh[b], 1);
        ebuf[lbase[b] + p] = key[i];
    }
}

__global__ __launch_bounds__(256)
void bucket_csr(const int* __restrict__ bbase, const int* __restrict__ ebuf,
                int* __restrict__ row, int* __restrict__ srcs, int N, int E)
{
    __shared__ int lh[128], lofs[128], lcur[128];
    const int b   = blockIdx.x;
    const int tid = threadIdx.x;
    const int beg = bbase[b], end = bbase[b + 1];

    if (tid < 128) lh[tid] = 0;
    __syncthreads();
    for (int e = beg + tid; e < end; e += 256)
        atomicAdd(&lh[ebuf[e] & 127], 1);
    __syncthreads();

    int v = (tid < 128) ? lh[tid] : 0;
    if (tid < 128) lofs[tid] = v;
    __syncthreads();
    for (int off = 1; off < 128; off <<= 1) {
        int add = 0;
        if (tid < 128 && tid >= off) add = lofs[tid - off];
        __syncthreads();
        if (tid < 128) lofs[tid] += add;
        __syncthreads();
    }
    if (tid < 128) {
        int ex = lofs[tid] - v;
        lcur[tid] = ex;
        int node = b * 128 + tid;
        if (node < N) row[node] = beg + ex;
    }
    if (b == 0 && tid == 0) row[N] = E;
    __syncthreads();

    for (int e = beg + tid; e < end; e += 256) {
        int pk = ebuf[e];
        int p = atomicAdd(&lcur[pk & 127], 1);
        srcs[beg + p] = pk >> 7;
    }
}

// ---------------------------------------------------------------------------
__global__ __launch_bounds__(256)
void pool_nodes(const unsigned short* __restrict__ hb,
                const float* __restrict__ bsum, const float* __restrict__ bsumsq,
                const float* __restrict__ gamma, const float* __restrict__ beta,
                float invN, const int* __restrict__ batch,
                float* __restrict__ pooled, int N)
{
    int d  = threadIdx.x & 63;
    int nl = threadIdx.x >> 6;
    int nb = blockIdx.x * 32;
    float mu  = bsum[d] * invN;
    float var = bsumsq[d] * invN - mu * mu;
    float s   = gamma[d] * rsqrtf(var + BN_EPS);
    float sh  = beta[d] - s * mu;
    float acc = 0.f;
    int cg = -1;
    #pragma unroll
    for (int r = 0; r < 8; r++) {
        int n = nb + nl * 8 + r;
        if (n >= N) break;
        int g = batch[n];
        if (g != cg) {
            if (cg >= 0) unsafeAtomicAdd(&pooled[(size_t)cg * 64 + d], acc);
            acc = 0.f; cg = g;
        }
        float v = __uint_as_float(((unsigned int)hb[(size_t)n * 64 + d]) << 16);
        acc += fmaxf(fmaf(v, s, sh), 0.f);
    }
    if (cg >= 0) unsafeAtomicAdd(&pooled[(size_t)cg * 64 + d], acc);
}

__global__ __launch_bounds__(256)
void pool_x(const float* __restrict__ x, const int* __restrict__ batch,
            float* __restrict__ px, int N)
{
    int f  = threadIdx.x & 31;
    int nl = threadIdx.x >> 5;
    int nb = blockIdx.x * 64;
    float acc = 0.f;
    int cg = -1;
    #pragma unroll
    for (int r = 0; r < 8; r++) {
        int n = nb + nl * 8 + r;
        if (n >= N) break;
        int g = batch[n];
        if (g != cg) {
            if (cg >= 0) unsafeAtomicAdd(&px[(size_t)cg * 32 + f], acc);
            acc = 0.f; cg = g;
        }
        acc += x[(size_t)n * 32 + f];
    }
    if (cg >= 0) unsafeAtomicAdd(&px[(size_t)cg * 32 + f], acc);
}

// ---------------------------------------------------------------------------
__global__ __launch_bounds__(256)
void head_kernel(const float* __restrict__ px, const float* __restrict__ pl,
                 const float* __restrict__ fcW0, const float* __restrict__ fcb0,
                 const float* __restrict__ fcW, const float* __restrict__ fcb,
                 const int* __restrict__ y, float* __restrict__ out, int G)
{
    int tid = blockIdx.x * 256 + threadIdx.x;
    int total = G * 10;
    if (tid < total) {
        int g = tid / 10, c = tid % 10;
        float acc = fcb0[c];
        const float* pxg = px + (size_t)g * 32;
        #pragma unroll
        for (int k = 0; k < 32; k++) acc = fmaf(pxg[k], fcW0[k * 10 + c], acc);
        #pragma unroll
        for (int i = 0; i < 4; i++) {
            acc += fcb[i * 10 + c];
            const float* pg = pl + ((size_t)i * G + g) * 64;
            const float* w  = fcW + i * 640;
            #pragma unroll
            for (int k = 0; k < 64; k++) acc = fmaf(pg[k], w[k * 10 + c], acc);
        }
        out[tid] = acc;
    } else if (tid < total + G) {
        out[tid] = (float)y[tid - total];
    }
}

// ---------------------------------------------------------------------------
extern "C" void kernel_launch(void* const* d_in, const int* in_sizes, int n_in,
                              void* d_out, int out_size, void* d_ws, size_t ws_size,
                              hipStream_t stream)
{
    const float* x     = (const float*)d_in[0];
    const int*   ei    = (const int*)  d_in[1];
    const int*   batch = (const int*)  d_in[2];
    const int*   y     = (const int*)  d_in[3];
    const float* W_enc = (const float*)d_in[4];
    const float* b_enc = (const float*)d_in[5];
    const float* W1    = (const float*)d_in[6];
    const float* b1    = (const float*)d_in[7];
    const float* g1    = (const float*)d_in[8];
    const float* be1   = (const float*)d_in[9];
    const float* W2    = (const float*)d_in[10];
    const float* b2    = (const float*)d_in[11];
    const float* gout  = (const float*)d_in[12];
    const float* bout  = (const float*)d_in[13];
    const float* fcW0  = (const float*)d_in[14];
    const float* fcb0  = (const float*)d_in[15];
    const float* fcW   = (const float*)d_in[16];
    const float* fcb   = (const float*)d_in[17];

    const int N = in_sizes[0] / 32;   // 100000
    const int E = in_sizes[1] / 2;    // 1600000
    const int G = in_sizes[3];        // 2000
    const int* src = ei;
    const int* dst = ei + E;
    const int NB = (N + 127) / 128;   // 782 buckets

    // ws layout: m bf16 | hb bf16 | stats | px | pl | row | srcs
    unsigned int* m  = (unsigned int*)d_ws;          // N*32 uints
    unsigned int* hb = m + (size_t)N * 32;           // N*32 uints
    float* stats = (float*)(hb + (size_t)N * 32);    // [4][2] x 128
    float* px    = stats + 1024;                     // G*32
    float* pl    = px + (size_t)G * 32;              // 4*G*64
    int*   row   = (int*)(pl + (size_t)4 * G * 64);  // N+1
    int*   srcs  = row + (N + 1);                    // E
    // CSR temps alias m (dead before layer-0 agg_bn writes m)
    int*   mi    = (int*)m;
    int*   bhist = mi;
    int*   bbase = mi + 1024;
    int*   bcur  = mi + 2048;
    int*   ebuf  = mi + 2048 + 800 * CURS_STRIDE;

    size_t zbytes = (size_t)(1024 + G * 32 + 4 * G * 64) * sizeof(float);
    hipMemsetAsync(stats, 0, zbytes, stream);
    hipMemsetAsync(bhist, 0, 1024 * sizeof(int), stream);

    // bucketed CSR build
    bucket_hist<<<160, 256, 0, stream>>>(dst, bhist, E, NB);
    bucket_scan<<<1, 1024, 0, stream>>>(bhist, bbase, bcur, NB);
    bucket_scatter<<<(E + 4095) / 4096, 256, 0, stream>>>(src, dst, bcur, ebuf, E, NB);
    bucket_csr<<<NB, 256, 0, stream>>>(bbase, ebuf, row, srcs, N, E);

    const int gb  = NB;                     // 128-row GEMM tiles
    const int ga  = (N * 8 + 255) / 256;    // gather blocks (3125)
    const float invN = 1.0f / (float)N;

    // encoder: hb = bf16(x @ W_enc + b_enc)
    mfma_gemm<32, 1, false><<<gb, 256, 0, stream>>>(
        x, nullptr, nullptr, nullptr, nullptr, 0.f,
        W_enc, b_enc, (unsigned short*)hb, nullptr, nullptr, N);
    pool_x<<<(N + 63) / 64, 256, 0, stream>>>(x, batch, px, N);

    for (int i = 0; i < 4; i++) {
        float* s1a = stats + (i * 2 + 0) * 128;
        float* s1b = s1a + 64;
        float* s2a = stats + (i * 2 + 1) * 128;
        float* s2b = s2a + 64;

        // m = bf16( t(hb[n]) + sum t(hb[nbr]) )   (standalone, max occupancy)
        if (i == 0) {
            agg_bn<false><<<ga, 256, 0, stream>>>(
                row, srcs, hb, nullptr, nullptr, nullptr, nullptr, 0.f, m, N);
        } else {
            float* p2a = stats + ((i - 1) * 2 + 1) * 128;
            float* p2b = p2a + 64;
            agg_bn<true><<<ga, 256, 0, stream>>>(
                row, srcs, hb, p2a, p2b,
                gout + (i - 1) * 64, bout + (i - 1) * 64, invN, m, N);
        }

        // m = bf16(m @ W1[i] + b1[i])  (in-place) + stats s1
        mfma_gemm<64, 0, true><<<gb, 256, 0, stream>>>(
            m, nullptr, nullptr, nullptr, nullptr, 0.f,
            W1 + (size_t)i * 4096, b1 + i * 64, (unsigned short*)m, s1a, s1b, N);

        // hb = bf16( relu(bn1(m)) @ W2[i] + b2[i] ) + stats s2
        mfma_gemm<64, 2, true><<<gb, 256, 0, stream>>>(
            m, s1a, s1b, g1 + i * 64, be1 + i * 64, invN,
            W2 + (size_t)i * 4096, b2 + i * 64, (unsigned short*)hb, s2a, s2b, N);

        // pl[i][g] += relu(bn2(hb))
        pool_nodes<<<(N + 31) / 32, 256, 0, stream>>>(
            (const unsigned short*)hb, s2a, s2b, gout + i * 64, bout + i * 64, invN,
            batch, pl + (size_t)i * G * 64, N);
    }

    head_kernel<<<(G * 10 + G + 255) / 256, 256, 0, stream>>>(
        px, pl, fcW0, fcb0, fcW, fcb, y, (float*)d_out, G);
}

// Round 13
// 568.563 us; speedup vs baseline: 5.3276x; 1.0215x over previous
//
#include <hip/hip_runtime.h>

// GIN final: round-8 structure (best measured: 564.6 us).
// - Bucketed CSR build (write-amp-free counting sort, padded cursors, LDS binning)
// - gin_gemm1: gather fused into GEMM1 (A-tile gathered into LDS, BN+ReLU folded
//   per neighbor, uint4 loads, 4-deep unroll), MFMA 16x16x32 bf16
// - mfma_gemm: encoder (fp32 in) and GEMM2 (BN+ReLU from raw stats)
// - bf16 storage for h and m; fp32 accumulation + fp32 BN stats everywhere
// - run-length pooling over sorted batch ids
// Lessons encoded: LDS fp32 atomics serialize (r9, 12x); stripping gather VALU
// work hurts (r10, latency-hiding); occupancy doesn't move the gather (r11);
// un-fusing doesn't either (r12). Gather = random-line concurrency bound.

#define BN_EPS 1e-5f
#define CURS_STRIDE 16

typedef __attribute__((ext_vector_type(8))) short short8;
typedef __attribute__((ext_vector_type(4))) float f32x4;

// ---- bf16 helpers (rne) ----
__device__ __forceinline__ unsigned int pack_bf16x2(float a, float b) {
    unsigned int ua = __float_as_uint(a);
    unsigned int ub = __float_as_uint(b);
    ua = (ua + 0x7FFFu + ((ua >> 16) & 1u)) >> 16;
    ub = (ub + 0x7FFFu + ((ub >> 16) & 1u)) >> 16;
    return ua | (ub << 16);
}
__device__ __forceinline__ unsigned short bf16_1(float f) {
    unsigned int u = __float_as_uint(f);
    u = (u + 0x7FFFu + ((u >> 16) & 1u)) >> 16;
    return (unsigned short)u;
}
__device__ __forceinline__ float2 unpack_bf16x2(unsigned int u) {
    float2 r;
    r.x = __uint_as_float(u << 16);
    r.y = __uint_as_float(u & 0xFFFF0000u);
    return r;
}

template<bool BN>
__device__ __forceinline__ void acc_row8(float (&acc)[8], uint4 p,
                                         const float* sc, const float* sh) {
    unsigned int pp[4] = {p.x, p.y, p.z, p.w};
    #pragma unroll
    for (int t = 0; t < 4; t++) {
        float2 f = unpack_bf16x2(pp[t]);
        if (BN) {
            f.x = fmaxf(fmaf(f.x, sc[2 * t],     sh[2 * t]),     0.f);
            f.y = fmaxf(fmaf(f.y, sc[2 * t + 1], sh[2 * t + 1]), 0.f);
        }
        acc[2 * t]     += f.x;
        acc[2 * t + 1] += f.y;
    }
}

// ---------------------------------------------------------------------------
// Fused GIN conv stage 1: A[n] = t(hb[n]) + sum_{s in nbrs(n)} t(hb[s]),
// out = bf16(A @ W1 + b1), column stats of out -> s1. t = BN?relu(v*s+sh):v.
// Block: 256 thr / 4 waves; tile 128 rows x 64 cols.
template<bool BN>
__global__ __launch_bounds__(256)
void gin_gemm1(const int* __restrict__ rowp, const int* __restrict__ srcs,
               const unsigned int* __restrict__ hb,
               const float* __restrict__ bsum, const float* __restrict__ bsumsq,
               const float* __restrict__ gamma, const float* __restrict__ beta,
               float invN,
               const float* __restrict__ W, const float* __restrict__ bias,
               unsigned short* __restrict__ out,
               float* __restrict__ stat_sum, float* __restrict__ stat_sumsq,
               int N)
{
    constexpr int AS = 72, WS = 72, KH = 2;
    __shared__ short a_lds[128 * AS];
    __shared__ short wt_lds[64 * WS];
    __shared__ float ssf[128];
    __shared__ float red[512];

    const int tid = threadIdx.x;
    const int nb  = blockIdx.x * 128;
    const int l   = tid & 63;
    const int w   = tid >> 6;
    const int ln  = l & 15;
    const int q   = l >> 4;

    if (BN) {
        if (tid < 64) {
            float mu  = bsum[tid] * invN;
            float var = bsumsq[tid] * invN - mu * mu;
            float s   = gamma[tid] * rsqrtf(var + BN_EPS);
            ssf[tid]      = s;
            ssf[64 + tid] = beta[tid] - s * mu;
        }
        __syncthreads();
    }

    // stage W^T bf16
    for (int idx = tid; idx < 64 * 64; idx += 256) {
        int k = idx >> 6, n = idx & 63;
        wt_lds[n * WS + k] = (short)bf16_1(W[idx]);
    }

    // gather A-tile: 8 lanes/row, uint4 (8 bf16) per lane
    const uint4* hb4 = (const uint4*)hb;
    const int cc = tid & 7;
    const int rl = tid >> 3;
    float sc[8], sh[8];
    if (BN) {
        #pragma unroll
        for (int j = 0; j < 8; j++) {
            sc[j] = ssf[cc * 8 + j];
            sh[j] = ssf[64 + cc * 8 + j];
        }
    }
    for (int it = 0; it < 4; it++) {
        int rloc = it * 32 + rl;
        int n = nb + rloc;
        float acc[8] = {0.f, 0.f, 0.f, 0.f, 0.f, 0.f, 0.f, 0.f};
        if (n < N) {
            uint4 p = hb4[(size_t)n * 8 + cc];
            acc_row8<BN>(acc, p, sc, sh);
            int e = rowp[n], end = rowp[n + 1];
            for (; e + 3 < end; e += 4) {
                int a0 = srcs[e], a1 = srcs[e + 1], a2 = srcs[e + 2], a3 = srcs[e + 3];
                uint4 p0 = hb4[(size_t)a0 * 8 + cc];
                uint4 p1 = hb4[(size_t)a1 * 8 + cc];
                uint4 p2 = hb4[(size_t)a2 * 8 + cc];
                uint4 p3 = hb4[(size_t)a3 * 8 + cc];
                acc_row8<BN>(acc, p0, sc, sh);
                acc_row8<BN>(acc, p1, sc, sh);
                acc_row8<BN>(acc, p2, sc, sh);
                acc_row8<BN>(acc, p3, sc, sh);
            }
            for (; e < end; e++) {
                uint4 pp = hb4[(size_t)srcs[e] * 8 + cc];
                acc_row8<BN>(acc, pp, sc, sh);
            }
        }
        uint4 o;
        o.x = pack_bf16x2(acc[0], acc[1]);
        o.y = pack_bf16x2(acc[2], acc[3]);
        o.z = pack_bf16x2(acc[4], acc[5]);
        o.w = pack_bf16x2(acc[6], acc[7]);
        *(uint4*)&a_lds[rloc * AS + cc * 8] = o;
    }
    __syncthreads();

    // fragments
    short8 afrag[2][KH], bfrag[4][KH];
    const int rw = w * 32;
    #pragma unroll
    for (int mt = 0; mt < 2; mt++)
        #pragma unroll
        for (int kh = 0; kh < KH; kh++)
            afrag[mt][kh] = *(const short8*)&a_lds[(rw + mt * 16 + ln) * AS + kh * 32 + q * 8];
    #pragma unroll
    for (int nt = 0; nt < 4; nt++)
        #pragma unroll
        for (int kh = 0; kh < KH; kh++)
            bfrag[nt][kh] = *(const short8*)&wt_lds[(nt * 16 + ln) * WS + kh * 32 + q * 8];

    f32x4 acc[2][4];
    #pragma unroll
    for (int nt = 0; nt < 4; nt++) {
        float bv = bias[nt * 16 + ln];
        #pragma unroll
        for (int mt = 0; mt < 2; mt++)
            acc[mt][nt] = (f32x4){bv, bv, bv, bv};
    }
    #pragma unroll
    for (int kh = 0; kh < KH; kh++)
        #pragma unroll
        for (int mt = 0; mt < 2; mt++)
            #pragma unroll
            for (int nt = 0; nt < 4; nt++)
                acc[mt][nt] = __builtin_amdgcn_mfma_f32_16x16x32_bf16(
                    afrag[mt][kh], bfrag[nt][kh], acc[mt][nt], 0, 0, 0);

    #pragma unroll
    for (int mt = 0; mt < 2; mt++)
        #pragma unroll
        for (int reg = 0; reg < 4; reg++) {
            int row = nb + rw + mt * 16 + q * 4 + reg;
            if (row < N)
                #pragma unroll
                for (int nt = 0; nt < 4; nt++)
                    out[(size_t)row * 64 + nt * 16 + ln] = bf16_1(acc[mt][nt][reg]);
        }

    // stats
    {
        float s1[4] = {0.f, 0.f, 0.f, 0.f};
        float s2[4] = {0.f, 0.f, 0.f, 0.f};
        #pragma unroll
        for (int mt = 0; mt < 2; mt++)
            #pragma unroll
            for (int reg = 0; reg < 4; reg++) {
                int row = nb + rw + mt * 16 + q * 4 + reg;
                if (row < N)
                    #pragma unroll
                    for (int nt = 0; nt < 4; nt++) {
                        float v = acc[mt][nt][reg];
                        s1[nt] += v;
                        s2[nt] += v * v;
                    }
            }
        #pragma unroll
        for (int nt = 0; nt < 4; nt++) {
            s1[nt] += __shfl_xor(s1[nt], 16);
            s1[nt] += __shfl_xor(s1[nt], 32);
            s2[nt] += __shfl_xor(s2[nt], 16);
            s2[nt] += __shfl_xor(s2[nt], 32);
        }
        __syncthreads();
        if (l < 16) {
            #pragma unroll
            for (int nt = 0; nt < 4; nt++) {
                red[w * 64 + nt * 16 + l]       = s1[nt];
                red[256 + w * 64 + nt * 16 + l] = s2[nt];
            }
        }
        __syncthreads();
        if (tid < 64) {
            float t1 = red[tid] + red[64 + tid] + red[128 + tid] + red[192 + tid];
            float t2 = red[256 + tid] + red[320 + tid] + red[384 + tid] + red[448 + tid];
            unsafeAtomicAdd(&stat_sum[tid],   t1);
            unsafeAtomicAdd(&stat_sumsq[tid], t2);
        }
    }
}

// ---------------------------------------------------------------------------
// Plain MFMA GEMM (encoder INK=1 fp32 input; GEMM2 INK=2 BN+ReLU from stats)
template<int K, int INK, bool STATS>
__global__ __launch_bounds__(256)
void mfma_gemm(const void* __restrict__ Av,
               const float* __restrict__ bn_sum, const float* __restrict__ bn_sumsq,
               const float* __restrict__ gamma, const float* __restrict__ beta,
               float invN,
               const float* __restrict__ W, const float* __restrict__ bias,
               unsigned short* __restrict__ out,
               float* __restrict__ stat_sum, float* __restrict__ stat_sumsq,
               int N)
{
    constexpr int AS  = K + 8;
    constexpr int WS  = K + 8;
    constexpr int CPR = K / 8;
    constexpr int KH  = K / 32;

    __shared__ short a_lds[128 * AS];
    __shared__ short wt_lds[64 * WS];
    __shared__ float ssf[128];
    __shared__ float red[512];

    const int tid = threadIdx.x;
    const int nb  = blockIdx.x * 128;
    const int l   = tid & 63;
    const int w   = tid >> 6;
    const int ln  = l & 15;
    const int q   = l >> 4;

    if (INK == 2) {
        if (tid < 64) {
            float mu  = bn_sum[tid] * invN;
            float var = bn_sumsq[tid] * invN - mu * mu;
            float s   = gamma[tid] * rsqrtf(var + BN_EPS);
            ssf[tid]      = s;
            ssf[64 + tid] = beta[tid] - s * mu;
        }
        __syncthreads();
    }

    for (int idx = tid; idx < K * 64; idx += 256) {
        int k = idx >> 6, n = idx & 63;
        wt_lds[n * WS + k] = (short)bf16_1(W[idx]);
    }

    for (int c = tid; c < 128 * CPR; c += 256) {
        int rloc = c / CPR;
        int j    = c % CPR;
        int row  = nb + rloc;
        uint4 p = make_uint4(0u, 0u, 0u, 0u);
        if (row < N) {
            if (INK == 1) {
                const float4* xr = (const float4*)Av;
                float4 f0 = xr[(size_t)row * (K / 4) + 2 * j];
                float4 f1 = xr[(size_t)row * (K / 4) + 2 * j + 1];
                p.x = pack_bf16x2(f0.x, f0.y); p.y = pack_bf16x2(f0.z, f0.w);
                p.z = pack_bf16x2(f1.x, f1.y); p.w = pack_bf16x2(f1.z, f1.w);
            } else {
                p = ((const uint4*)Av)[(size_t)row * CPR + j];
                if (INK == 2) {
                    int k0 = j * 8;
                    unsigned int* pp = (unsigned int*)&p;
                    #pragma unroll
                    for (int t = 0; t < 4; t++) {
                        float2 f = unpack_bf16x2(pp[t]);
                        int k = k0 + 2 * t;
                        f.x = fmaxf(fmaf(f.x, ssf[k],     ssf[64 + k]),     0.f);
                        f.y = fmaxf(fmaf(f.y, ssf[k + 1], ssf[64 + k + 1]), 0.f);
                        pp[t] = pack_bf16x2(f.x, f.y);
                    }
                }
            }
        }
        *(uint4*)&a_lds[rloc * AS + j * 8] = p;
    }
    __syncthreads();

    short8 afrag[2][KH], bfrag[4][KH];
    const int rw = w * 32;
    #pragma unroll
    for (int mt = 0; mt < 2; mt++)
        #pragma unroll
        for (int kh = 0; kh < KH; kh++)
            afrag[mt][kh] = *(const short8*)&a_lds[(rw + mt * 16 + ln) * AS + kh * 32 + q * 8];
    #pragma unroll
    for (int nt = 0; nt < 4; nt++)
        #pragma unroll
        for (int kh = 0; kh < KH; kh++)
            bfrag[nt][kh] = *(const short8*)&wt_lds[(nt * 16 + ln) * WS + kh * 32 + q * 8];

    f32x4 acc[2][4];
    #pragma unroll
    for (int nt = 0; nt < 4; nt++) {
        float bv = bias[nt * 16 + ln];
        #pragma unroll
        for (int mt = 0; mt < 2; mt++)
            acc[mt][nt] = (f32x4){bv, bv, bv, bv};
    }
    #pragma unroll
    for (int kh = 0; kh < KH; kh++)
        #pragma unroll
        for (int mt = 0; mt < 2; mt++)
            #pragma unroll
            for (int nt = 0; nt < 4; nt++)
                acc[mt][nt] = __builtin_amdgcn_mfma_f32_16x16x32_bf16(
                    afrag[mt][kh], bfrag[nt][kh], acc[mt][nt], 0, 0, 0);

    #pragma unroll
    for (int mt = 0; mt < 2; mt++)
        #pragma unroll
        for (int reg = 0; reg < 4; reg++) {
            int row = nb + rw + mt * 16 + q * 4 + reg;
            if (row < N)
                #pragma unroll
                for (int nt = 0; nt < 4; nt++)
                    out[(size_t)row * 64 + nt * 16 + ln] = bf16_1(acc[mt][nt][reg]);
        }

    if (STATS) {
        float s1[4] = {0.f, 0.f, 0.f, 0.f};
        float s2[4] = {0.f, 0.f, 0.f, 0.f};
        #pragma unroll
        for (int mt = 0; mt < 2; mt++)
            #pragma unroll
            for (int reg = 0; reg < 4; reg++) {
                int row = nb + rw + mt * 16 + q * 4 + reg;
                if (row < N)
                    #pragma unroll
                    for (int nt = 0; nt < 4; nt++) {
                        float v = acc[mt][nt][reg];
                        s1[nt] += v;
                        s2[nt] += v * v;
                    }
            }
        #pragma unroll
        for (int nt = 0; nt < 4; nt++) {
            s1[nt] += __shfl_xor(s1[nt], 16);
            s1[nt] += __shfl_xor(s1[nt], 32);
            s2[nt] += __shfl_xor(s2[nt], 16);
            s2[nt] += __shfl_xor(s2[nt], 32);
        }
        __syncthreads();
        if (l < 16) {
            #pragma unroll
            for (int nt = 0; nt < 4; nt++) {
                red[w * 64 + nt * 16 + l]       = s1[nt];
                red[256 + w * 64 + nt * 16 + l] = s2[nt];
            }
        }
        __syncthreads();
        if (tid < 64) {
            float t1 = red[tid] + red[64 + tid] + red[128 + tid] + red[192 + tid];
            float t2 = red[256 + tid] + red[320 + tid] + red[384 + tid] + red[448 + tid];
            unsafeAtomicAdd(&stat_sum[tid],   t1);
            unsafeAtomicAdd(&stat_sumsq[tid], t2);
        }
    }
}

// ---------------------------------------------------------------------------
// Bucketed CSR build (bucket = dst>>7, <=800 buckets)
__global__ __launch_bounds__(256)
void bucket_hist(const int* __restrict__ dst, int* __restrict__ bhist,
                 int E, int nb)
{
    __shared__ int lh[1024];
    for (int i = threadIdx.x; i < 1024; i += 256) lh[i] = 0;
    __syncthreads();
    for (int e = blockIdx.x * 256 + threadIdx.x; e < E; e += gridDim.x * 256)
        atomicAdd(&lh[dst[e] >> 7], 1);
    __syncthreads();
    for (int i = threadIdx.x; i < nb; i += 256)
        if (lh[i]) atomicAdd(&bhist[i], lh[i]);
}

__global__ __launch_bounds__(1024)
void bucket_scan(const int* __restrict__ bhist, int* __restrict__ bbase,
                 int* __restrict__ bcur, int nb)
{
    __shared__ int sm[1024];
    int t = threadIdx.x;
    int v = (t < nb) ? bhist[t] : 0;
    sm[t] = v; __syncthreads();
    for (int off = 1; off < 1024; off <<= 1) {
        int add = (t >= off) ? sm[t - off] : 0;
        __syncthreads();
        sm[t] += add;
        __syncthreads();
    }
    if (t <= nb) {
        int ex = sm[t] - v;
        bbase[t] = ex;
        if (t < nb) bcur[t * CURS_STRIDE] = ex;
    }
}

__global__ __launch_bounds__(256)
void bucket_scatter(const int* __restrict__ src, const int* __restrict__ dst,
                    int* __restrict__ bcur, int* __restrict__ ebuf,
                    int E, int nb)
{
    constexpr int CH = 4096;
    __shared__ int            key[CH];
    __shared__ unsigned short bid[CH];
    __shared__ int lh[800];
    __shared__ int lbase[800];

    const int t    = threadIdx.x;
    const int base = blockIdx.x * CH;
    const int cnt  = min(CH, E - base);

    for (int i = t; i < nb; i += 256) lh[i] = 0;
    __syncthreads();

    for (int i = t; i < cnt; i += 256) {
        int d = dst[base + i];
        int s = src[base + i];
        int b = d >> 7;
        key[i] = (s << 7) | (d & 127);
        bid[i] = (unsigned short)b;
        atomicAdd(&lh[b], 1);
    }
    __syncthreads();

    for (int i = t; i < nb; i += 256) {
        int c = lh[i];
        if (c) lbase[i] = atomicAdd(&bcur[i * CURS_STRIDE], c);
        lh[i] = 0;
    }
    __syncthreads();

    for (int i = t; i < cnt; i += 256) {
        int b = bid[i];
        int p = atomicAdd(&lh[b], 1);
        ebuf[lbase[b] + p] = key[i];
    }
}

__global__ __launch_bounds__(256)
void bucket_csr(const int* __restrict__ bbase, const int* __restrict__ ebuf,
                int* __restrict__ row, int* __restrict__ srcs, int N, int E)
{
    __shared__ int lh[128], lofs[128], lcur[128];
    const int b   = blockIdx.x;
    const int tid = threadIdx.x;
    const int beg = bbase[b], end = bbase[b + 1];

    if (tid < 128) lh[tid] = 0;
    __syncthreads();
    for (int e = beg + tid; e < end; e += 256)
        atomicAdd(&lh[ebuf[e] & 127], 1);
    __syncthreads();

    int v = (tid < 128) ? lh[tid] : 0;
    if (tid < 128) lofs[tid] = v;
    __syncthreads();
    for (int off = 1; off < 128; off <<= 1) {
        int add = 0;
        if (tid < 128 && tid >= off) add = lofs[tid - off];
        __syncthreads();
        if (tid < 128) lofs[tid] += add;
        __syncthreads();
    }
    if (tid < 128) {
        int ex = lofs[tid] - v;
        lcur[tid] = ex;
        int node = b * 128 + tid;
        if (node < N) row[node] = beg + ex;
    }
    if (b == 0 && tid == 0) row[N] = E;
    __syncthreads();

    for (int e = beg + tid; e < end; e += 256) {
        int pk = ebuf[e];
        int p = atomicAdd(&lcur[pk & 127], 1);
        srcs[beg + p] = pk >> 7;
    }
}

// ---------------------------------------------------------------------------
__global__ __launch_bounds__(256)
void pool_nodes(const unsigned short* __restrict__ hb,
                const float* __restrict__ bsum, const float* __restrict__ bsumsq,
                const float* __restrict__ gamma, const float* __restrict__ beta,
                float invN, const int* __restrict__ batch,
                float* __restrict__ pooled, int N)
{
    int d  = threadIdx.x & 63;
    int nl = threadIdx.x >> 6;
    int nb = blockIdx.x * 32;
    float mu  = bsum[d] * invN;
    float var = bsumsq[d] * invN - mu * mu;
    float s   = gamma[d] * rsqrtf(var + BN_EPS);
    float sh  = beta[d] - s * mu;
    float acc = 0.f;
    int cg = -1;
    #pragma unroll
    for (int r = 0; r < 8; r++) {
        int n = nb + nl * 8 + r;
        if (n >= N) break;
        int g = batch[n];
        if (g != cg) {
            if (cg >= 0) unsafeAtomicAdd(&pooled[(size_t)cg * 64 + d], acc);
            acc = 0.f; cg = g;
        }
        float v = __uint_as_float(((unsigned int)hb[(size_t)n * 64 + d]) << 16);
        acc += fmaxf(fmaf(v, s, sh), 0.f);
    }
    if (cg >= 0) unsafeAtomicAdd(&pooled[(size_t)cg * 64 + d], acc);
}

__global__ __launch_bounds__(256)
void pool_x(const float* __restrict__ x, const int* __restrict__ batch,
            float* __restrict__ px, int N)
{
    int f  = threadIdx.x & 31;
    int nl = threadIdx.x >> 5;
    int nb = blockIdx.x * 64;
    float acc = 0.f;
    int cg = -1;
    #pragma unroll
    for (int r = 0; r < 8; r++) {
        int n = nb + nl * 8 + r;
        if (n >= N) break;
        int g = batch[n];
        if (g != cg) {
            if (cg >= 0) unsafeAtomicAdd(&px[(size_t)cg * 32 + f], acc);
            acc = 0.f; cg = g;
        }
        acc += x[(size_t)n * 32 + f];
    }
    if (cg >= 0) unsafeAtomicAdd(&px[(size_t)cg * 32 + f], acc);
}

// ---------------------------------------------------------------------------
__global__ __launch_bounds__(256)
void head_kernel(const float* __restrict__ px, const float* __restrict__ pl,
                 const float* __restrict__ fcW0, const float* __restrict__ fcb0,
                 const float* __restrict__ fcW, const float* __restrict__ fcb,
                 const int* __restrict__ y, float* __restrict__ out, int G)
{
    int tid = blockIdx.x * 256 + threadIdx.x;
    int total = G * 10;
    if (tid < total) {
        int g = tid / 10, c = tid % 10;
        float acc = fcb0[c];
        const float* pxg = px + (size_t)g * 32;
        #pragma unroll
        for (int k = 0; k < 32; k++) acc = fmaf(pxg[k], fcW0[k * 10 + c], acc);
        #pragma unroll
        for (int i = 0; i < 4; i++) {
            acc += fcb[i * 10 + c];
            const float* pg = pl + ((size_t)i * G + g) * 64;
            const float* w  = fcW + i * 640;
            #pragma unroll
            for (int k = 0; k < 64; k++) acc = fmaf(pg[k], w[k * 10 + c], acc);
        }
        out[tid] = acc;
    } else if (tid < total + G) {
        out[tid] = (float)y[tid - total];
    }
}

// ---------------------------------------------------------------------------
extern "C" void kernel_launch(void* const* d_in, const int* in_sizes, int n_in,
                              void* d_out, int out_size, void* d_ws, size_t ws_size,
                              hipStream_t stream)
{
    const float* x     = (const float*)d_in[0];
    const int*   ei    = (const int*)  d_in[1];
    const int*   batch = (const int*)  d_in[2];
    const int*   y     = (const int*)  d_in[3];
    const float* W_enc = (const float*)d_in[4];
    const float* b_enc = (const float*)d_in[5];
    const float* W1    = (const float*)d_in[6];
    const float* b1    = (const float*)d_in[7];
    const float* g1    = (const float*)d_in[8];
    const float* be1   = (const float*)d_in[9];
    const float* W2    = (const float*)d_in[10];
    const float* b2    = (const float*)d_in[11];
    const float* gout  = (const float*)d_in[12];
    const float* bout  = (const float*)d_in[13];
    const float* fcW0  = (const float*)d_in[14];
    const float* fcb0  = (const float*)d_in[15];
    const float* fcW   = (const float*)d_in[16];
    const float* fcb   = (const float*)d_in[17];

    const int N = in_sizes[0] / 32;   // 100000
    const int E = in_sizes[1] / 2;    // 1600000
    const int G = in_sizes[3];        // 2000
    const int* src = ei;
    const int* dst = ei + E;
    const int NB = (N + 127) / 128;   // 782 buckets

    // ws layout: m bf16 | hb bf16 | stats | px | pl | row | srcs
    unsigned int* m  = (unsigned int*)d_ws;          // N*32 uints
    unsigned int* hb = m + (size_t)N * 32;           // N*32 uints
    float* stats = (float*)(hb + (size_t)N * 32);    // [4][2] x 128
    float* px    = stats + 1024;                     // G*32
    float* pl    = px + (size_t)G * 32;              // 4*G*64
    int*   row   = (int*)(pl + (size_t)4 * G * 64);  // N+1
    int*   srcs  = row + (N + 1);                    // E
    // CSR temps alias m (dead before layer-0 gin_gemm1 writes m)
    int*   mi    = (int*)m;
    int*   bhist = mi;
    int*   bbase = mi + 1024;
    int*   bcur  = mi + 2048;
    int*   ebuf  = mi + 2048 + 800 * CURS_STRIDE;

    size_t zbytes = (size_t)(1024 + G * 32 + 4 * G * 64) * sizeof(float);
    hipMemsetAsync(stats, 0, zbytes, stream);
    hipMemsetAsync(bhist, 0, 1024 * sizeof(int), stream);

    // bucketed CSR build
    bucket_hist<<<160, 256, 0, stream>>>(dst, bhist, E, NB);
    bucket_scan<<<1, 1024, 0, stream>>>(bhist, bbase, bcur, NB);
    bucket_scatter<<<(E + 4095) / 4096, 256, 0, stream>>>(src, dst, bcur, ebuf, E, NB);
    bucket_csr<<<NB, 256, 0, stream>>>(bbase, ebuf, row, srcs, N, E);

    const int gb = NB;
    const float invN = 1.0f / (float)N;

    // encoder: hb = bf16(x @ W_enc + b_enc)
    mfma_gemm<32, 1, false><<<gb, 256, 0, stream>>>(
        x, nullptr, nullptr, nullptr, nullptr, 0.f,
        W_enc, b_enc, (unsigned short*)hb, nullptr, nullptr, N);
    pool_x<<<(N + 63) / 64, 256, 0, stream>>>(x, batch, px, N);

    for (int i = 0; i < 4; i++) {
        float* s1a = stats + (i * 2 + 0) * 128;
        float* s1b = s1a + 64;
        float* s2a = stats + (i * 2 + 1) * 128;
        float* s2b = s2a + 64;

        // m = bf16( (t(hb[n]) + sum t(hb[nbr])) @ W1 + b1 ) + stats s1 (fused)
        if (i == 0) {
            gin_gemm1<false><<<gb, 256, 0, stream>>>(
                row, srcs, hb, nullptr, nullptr, nullptr, nullptr, 0.f,
                W1 + (size_t)i * 4096, b1 + i * 64, (unsigned short*)m, s1a, s1b, N);
        } else {
            float* p2a = stats + ((i - 1) * 2 + 1) * 128;
            float* p2b = p2a + 64;
            gin_gemm1<true><<<gb, 256, 0, stream>>>(
                row, srcs, hb, p2a, p2b,
                gout + (i - 1) * 64, bout + (i - 1) * 64, invN,
                W1 + (size_t)i * 4096, b1 + i * 64, (unsigned short*)m, s1a, s1b, N);
        }

        // hb = bf16( relu(bn1(m)) @ W2[i] + b2[i] ) + stats s2
        mfma_gemm<64, 2, true><<<gb, 256, 0, stream>>>(
            m, s1a, s1b, g1 + i * 64, be1 + i * 64, invN,
            W2 + (size_t)i * 4096, b2 + i * 64, (unsigned short*)hb, s2a, s2b, N);

        // pl[i][g] += relu(bn2(hb))
        pool_nodes<<<(N + 31) / 32, 256, 0, stream>>>(
            (const unsigned short*)hb, s2a, s2b, gout + i * 64, bout + i * 64, invN,
            batch, pl + (size_t)i * G * 64, N);
    }

    head_kernel<<<(G * 10 + G + 255) / 256, 256, 0, stream>>>(
        px, pl, fcW0, fcb0, fcW, fcb, y, (float*)d_out, G);
}